// Round 1
// baseline (538.414 us; speedup 1.0000x reference)
//
#include <hip/hip_runtime.h>

// MMD with 7-bandwidth Gaussian kernel, x,y: [8192,128] fp32.
// out = mean(Kxx) + mean(Kyy) - 2*mean(Kxy), K = sum_g exp(-g * max(d2, 1e-30))
//
// Strategy: fused GEMM-like fp32 kernel (no fp32 MFMA on CDNA4 -> VALU).
// - 128x128 pair tiles, BK=32 LDS staging (k-major, +4 pad), 8x8 per-thread
//   register tile.
// - kxx/kyy symmetric: only upper-triangle tiles, weight 2 off-diagonal.
// - Epilogue: d = n_i + n_j - 2*dot, clamp 1e-30, 7x __expf, local fp32 sum,
//   block-reduce in double, one atomicAdd(double) per block.
// - Final scalar = acc / 8192^2.

#define N_PTS 8192
#define D 128
#define BM 128
#define BN 128
#define BK 32
#define LDSW 132          // +4 pad: breaks bank alignment of the k-stride
#define TILES 64          // 8192/128
#define TRI 2080          // 64*65/2

__global__ __launch_bounds__(256) void norms_kernel(const float* __restrict__ x,
                                                    const float* __restrict__ y,
                                                    float* __restrict__ nx,
                                                    float* __restrict__ ny) {
  int tid = threadIdx.x;
  int g = tid & 3;                       // 4 threads per row
  int row = ((int)blockIdx.x & 127) * 64 + (tid >> 2);
  int arr = (int)blockIdx.x >> 7;        // 0 = x, 1 = y
  const float* src = arr ? y : x;
  const float4* p = (const float4*)(src + (size_t)row * D) + g;
  float s = 0.f;
  #pragma unroll
  for (int i = 0; i < 8; i++) {
    float4 v = p[i * 4];
    s += v.x * v.x + v.y * v.y + v.z * v.z + v.w * v.w;
  }
  s += __shfl_xor(s, 1);
  s += __shfl_xor(s, 2);
  if (g == 0) (arr ? ny : nx)[row] = s;
}

__global__ __launch_bounds__(256) void mmd_kernel(const float* __restrict__ X,
                                                  const float* __restrict__ Y,
                                                  const float* __restrict__ nx,
                                                  const float* __restrict__ ny,
                                                  double* __restrict__ acc_out) {
  __shared__ float As[BK][LDSW];
  __shared__ float Bs[BK][LDSW];
  __shared__ double red[256];

  int bid = blockIdx.x;
  const float *A, *B, *nA, *nB;
  float w;
  int ib, jb;
  if (bid < 2 * TRI) {
    int t = (bid < TRI) ? bid : bid - TRI;
    int r = 0;
    while (t >= TILES - r) { t -= TILES - r; r++; }   // upper-tri decode
    ib = r; jb = r + t;
    if (bid < TRI) { A = X; B = X; nA = nx; nB = nx; }
    else           { A = Y; B = Y; nA = ny; nB = ny; }
    w = (ib == jb) ? 1.0f : 2.0f;
  } else {
    int t = bid - 2 * TRI;
    ib = t >> 6; jb = t & 63;
    A = X; B = Y; nA = nx; nB = ny;
    w = -2.0f;
  }

  int tid = threadIdx.x;
  int tx = tid & 15, ty = tid >> 4;
  int rm = ty * 8, cn = tx * 8;

  const float* Ab = A + (size_t)ib * BM * D;
  const float* Bb = B + (size_t)jb * BN * D;

  float acc[8][8];
  #pragma unroll
  for (int u = 0; u < 8; u++)
    #pragma unroll
    for (int v = 0; v < 8; v++) acc[u][v] = 0.f;

  for (int kc = 0; kc < D; kc += BK) {
    __syncthreads();
    #pragma unroll
    for (int l = 0; l < 4; l++) {
      int idx = tid + 256 * l;           // 0..1023 -> (row, float4-in-row)
      int row = idx >> 3, f4 = idx & 7;
      float4 va = *(const float4*)(Ab + (size_t)row * D + kc + f4 * 4);
      float4 vb = *(const float4*)(Bb + (size_t)row * D + kc + f4 * 4);
      int k0 = f4 * 4;
      As[k0 + 0][row] = va.x; As[k0 + 1][row] = va.y;
      As[k0 + 2][row] = va.z; As[k0 + 3][row] = va.w;
      Bs[k0 + 0][row] = vb.x; Bs[k0 + 1][row] = vb.y;
      Bs[k0 + 2][row] = vb.z; Bs[k0 + 3][row] = vb.w;
    }
    __syncthreads();
    #pragma unroll 4
    for (int k = 0; k < BK; k++) {
      float4 a0 = *(const float4*)&As[k][rm];
      float4 a1 = *(const float4*)&As[k][rm + 4];
      float4 b0 = *(const float4*)&Bs[k][cn];
      float4 b1 = *(const float4*)&Bs[k][cn + 4];
      float a[8] = {a0.x, a0.y, a0.z, a0.w, a1.x, a1.y, a1.z, a1.w};
      float b[8] = {b0.x, b0.y, b0.z, b0.w, b1.x, b1.y, b1.z, b1.w};
      #pragma unroll
      for (int u = 0; u < 8; u++)
        #pragma unroll
        for (int v = 0; v < 8; v++)
          acc[u][v] = fmaf(a[u], b[v], acc[u][v]);
    }
  }

  float na[8], nb[8];
  #pragma unroll
  for (int u = 0; u < 8; u++) na[u] = nA[ib * BM + rm + u];
  #pragma unroll
  for (int v = 0; v < 8; v++) nb[v] = nB[jb * BN + cn + v];

  float lsum = 0.f;
  #pragma unroll
  for (int u = 0; u < 8; u++) {
    #pragma unroll
    for (int v = 0; v < 8; v++) {
      float d = fmaf(-2.f, acc[u][v], na[u] + nb[v]);
      d = fmaxf(d, 1e-30f);
      lsum += __expf(d * -0.001f);
      lsum += __expf(d * -0.01f);
      lsum += __expf(d * -0.1f);
      lsum += __expf(d * -1.0f);
      lsum += __expf(d * -10.0f);
      lsum += __expf(d * -100.0f);
      lsum += __expf(d * -1000.0f);
    }
  }

  red[tid] = (double)lsum * (double)w;
  __syncthreads();
  #pragma unroll
  for (int s = 128; s > 0; s >>= 1) {
    if (tid < s) red[tid] += red[tid + s];
    __syncthreads();
  }
  if (tid == 0) atomicAdd(acc_out, red[0]);
}

__global__ void finalize_kernel(const double* __restrict__ acc,
                                float* __restrict__ out) {
  out[0] = (float)(acc[0] * (1.0 / ((double)N_PTS * (double)N_PTS)));
}

extern "C" void kernel_launch(void* const* d_in, const int* in_sizes, int n_in,
                              void* d_out, int out_size, void* d_ws, size_t ws_size,
                              hipStream_t stream) {
  const float* x = (const float*)d_in[0];
  const float* y = (const float*)d_in[1];
  float* out = (float*)d_out;

  char* ws = (char*)d_ws;
  double* acc = (double*)ws;                 // 8 B accumulator
  float* nx = (float*)(ws + 256);            // 8192 floats
  float* ny = nx + N_PTS;                    // 8192 floats

  hipMemsetAsync(acc, 0, sizeof(double), stream);
  hipLaunchKernelGGL(norms_kernel, dim3(256), dim3(256), 0, stream, x, y, nx, ny);
  hipLaunchKernelGGL(mmd_kernel, dim3(2 * TRI + TILES * TILES), dim3(256), 0,
                     stream, x, y, nx, ny, acc);
  hipLaunchKernelGGL(finalize_kernel, dim3(1), dim3(1), 0, stream, acc, out);
}

// Round 2
// 269.414 us; speedup vs baseline: 1.9985x; 1.9985x over previous
//
#include <hip/hip_runtime.h>

// MMD, 7-gamma Gaussian kernel, x,y: [8192,128] fp32.
// Round 2: bf16 hi/lo split-precision MFMA for the Gram matrices.
//   dot(a,b) = GEMM over K'=256 bf16 ([hi(a)|lo(a)] . [hi(b)|lo(b)]) in f32 MFMA acc
//   -> per-product error ~2^-17 (better than fp32 chain), 2.5 PF pipe instead of 157 TF.
// Diagonal (d_ii ~ fp32 noise, exp(-1000 d) sensitive) patched by a separate fp32
// kernel replicating round-1's exact sequential-FMA rounding; i==j masked in tiles.
// Epilogue: when all-lane d > 110, exp(-g*d) == 0.0f exactly for g>=1 (ref too) ->
//   only 3 exps (g=0.001,0.01,0.1).

#define N_PTS 8192
#define D 128
#define TILES 64
#define TRI 2080
#define NBLK (2 * TRI + TILES * TILES)

typedef __attribute__((ext_vector_type(8))) short bf16x8;
typedef __attribute__((ext_vector_type(8))) unsigned short u16x8;
typedef __attribute__((ext_vector_type(4))) float f32x4;

__device__ __forceinline__ unsigned short f2bf(float a) {  // RNE
  unsigned u = __float_as_uint(a);
  return (unsigned short)((u + 0x7FFFu + ((u >> 16) & 1u)) >> 16);
}
__device__ __forceinline__ float bf2f(unsigned short b) {
  return __uint_as_float(((unsigned)b) << 16);
}

__global__ __launch_bounds__(256) void norms_kernel(const float* __restrict__ x,
                                                    const float* __restrict__ y,
                                                    float* __restrict__ nx,
                                                    float* __restrict__ ny) {
  int tid = threadIdx.x;
  int g = tid & 3;
  int row = ((int)blockIdx.x & 127) * 64 + (tid >> 2);
  int arr = (int)blockIdx.x >> 7;
  const float* src = arr ? y : x;
  const float4* p = (const float4*)(src + (size_t)row * D) + g;
  float s = 0.f;
  #pragma unroll
  for (int i = 0; i < 8; i++) {
    float4 v = p[i * 4];
    s += v.x * v.x + v.y * v.y + v.z * v.z + v.w * v.w;
  }
  s += __shfl_xor(s, 1);
  s += __shfl_xor(s, 2);
  if (g == 0) (arr ? ny : nx)[row] = s;
}

__global__ __launch_bounds__(256) void mmd_kernel(const float* __restrict__ X,
                                                  const float* __restrict__ Y,
                                                  const float* __restrict__ nx,
                                                  const float* __restrict__ ny,
                                                  double* __restrict__ acc_out) {
  __shared__ unsigned short As[128 * 64];   // swizzled [row][k2], one K-chunk
  __shared__ unsigned short Bs[128 * 64];
  __shared__ double red[256];

  int bid = blockIdx.x;
  const float *A, *B, *nA, *nB;
  float w;
  int ib, jb;
  bool isdiag = false;
  if (bid < 2 * TRI) {
    int t = (bid < TRI) ? bid : bid - TRI;
    int r = 0;
    while (t >= TILES - r) { t -= TILES - r; r++; }   // upper-tri decode
    ib = r; jb = r + t;
    if (bid < TRI) { A = X; B = X; nA = nx; nB = nx; }
    else           { A = Y; B = Y; nA = ny; nB = ny; }
    isdiag = (ib == jb);
    w = isdiag ? 1.0f : 2.0f;
  } else {
    int t = bid - 2 * TRI;
    ib = t >> 6; jb = t & 63;
    A = X; B = Y; nA = nx; nB = ny;
    w = -2.0f;
  }

  int tid = threadIdx.x;
  int lane = tid & 63;
  int wv = tid >> 6;
  int wm = wv >> 1, wn = wv & 1;          // 2x2 waves, 64x64 out each
  int r16 = lane & 15, g4 = lane >> 4;

  const float* Ab = A + (size_t)ib * 128 * D;
  const float* Bb = B + (size_t)jb * 128 * D;

  f32x4 acc[4][4];
  #pragma unroll
  for (int m = 0; m < 4; m++)
    #pragma unroll
    for (int n = 0; n < 4; n++) acc[m][n] = (f32x4){0.f, 0.f, 0.f, 0.f};

  // logical K' = 256 bf16: cols [0,128) = hi(k), [128,256) = lo(k); 4 chunks of 64
  #pragma unroll 1
  for (int kc = 0; kc < 4; kc++) {
    int k0f = (kc & 1) * 64;        // fp32 k base for this chunk
    bool ishi = (kc < 2);
    __syncthreads();                // protect previous chunk's reads
    #pragma unroll
    for (int s = 0; s < 4; s++) {
      int slot = tid + s * 256;     // 1024 slots = 128 rows x 8 x (8 bf16)
      int row = slot >> 3;
      int k2 = (slot & 7) * 8;
      const float* pa = Ab + row * D + k0f + k2;
      const float* pb = Bb + row * D + k0f + k2;
      float4 a0 = *(const float4*)pa;
      float4 a1 = *(const float4*)(pa + 4);
      float4 b0 = *(const float4*)pb;
      float4 b1 = *(const float4*)(pb + 4);
      float av[8] = {a0.x, a0.y, a0.z, a0.w, a1.x, a1.y, a1.z, a1.w};
      float bv[8] = {b0.x, b0.y, b0.z, b0.w, b1.x, b1.y, b1.z, b1.w};
      u16x8 ua, ub;
      #pragma unroll
      for (int j = 0; j < 8; j++) {
        unsigned short ha = f2bf(av[j]);
        unsigned short hb = f2bf(bv[j]);
        if (ishi) {
          ua[j] = (short)ha; ub[j] = (short)hb;
        } else {
          ua[j] = f2bf(av[j] - bf2f(ha));
          ub[j] = f2bf(bv[j] - bf2f(hb));
        }
      }
      int boff = row * 128 + ((k2 * 2) ^ ((row & 7) << 4));  // XOR swizzle
      *(u16x8*)((char*)As + boff) = ua;
      *(u16x8*)((char*)Bs + boff) = ub;
    }
    __syncthreads();
    #pragma unroll
    for (int ks = 0; ks < 2; ks++) {
      bf16x8 af[4], bfr[4];
      int kb = ks * 64 + g4 * 16;   // byte-in-row for this lane's k-slice
      #pragma unroll
      for (int m = 0; m < 4; m++) {
        int row = wm * 64 + m * 16 + r16;
        af[m] = *(const bf16x8*)((const char*)As + row * 128 + (kb ^ ((row & 7) << 4)));
      }
      #pragma unroll
      for (int n = 0; n < 4; n++) {
        int row = wn * 64 + n * 16 + r16;
        bfr[n] = *(const bf16x8*)((const char*)Bs + row * 128 + (kb ^ ((row & 7) << 4)));
      }
      #pragma unroll
      for (int m = 0; m < 4; m++)
        #pragma unroll
        for (int n = 0; n < 4; n++)
          acc[m][n] = __builtin_amdgcn_mfma_f32_16x16x32_bf16(af[m], bfr[n], acc[m][n], 0, 0, 0);
    }
  }

  // epilogue: d = n_i + n_j - 2*dot; C/D layout col=lane&15, row=(lane>>4)*4+reg
  const float* nArow = nA + ib * 128;
  const float* nBrow = nB + jb * 128;
  float nb4[4];
  #pragma unroll
  for (int n = 0; n < 4; n++) nb4[n] = nBrow[wn * 64 + n * 16 + r16];

  float lsum = 0.f;
  #pragma unroll
  for (int m = 0; m < 4; m++) {
    float na4[4];
    #pragma unroll
    for (int r = 0; r < 4; r++) na4[r] = nArow[wm * 64 + m * 16 + g4 * 4 + r];
    float dv[4][4];
    float dmin = 3.0e38f;
    #pragma unroll
    for (int n = 0; n < 4; n++) {
      #pragma unroll
      for (int r = 0; r < 4; r++) {
        float dd = fmaf(-2.f, acc[m][n][r], na4[r] + nb4[n]);
        dd = fmaxf(dd, 1e-30f);
        int rl = wm * 64 + m * 16 + g4 * 4 + r;
        int cl = wn * 64 + n * 16 + r16;
        if (isdiag && rl == cl) dd = 1e30f;   // diag handled by diag_kernel
        dv[n][r] = dd;
        dmin = fminf(dmin, dd);
      }
    }
    if (__all(dmin > 110.f)) {
      // exp(-g*d) == 0.0f exactly for g>=1 when d>110 (also 0 in reference)
      #pragma unroll
      for (int n = 0; n < 4; n++)
        #pragma unroll
        for (int r = 0; r < 4; r++) {
          float dd = dv[n][r];
          lsum += __expf(dd * -0.001f);
          lsum += __expf(dd * -0.01f);
          lsum += __expf(dd * -0.1f);
        }
    } else {
      #pragma unroll
      for (int n = 0; n < 4; n++)
        #pragma unroll
        for (int r = 0; r < 4; r++) {
          float dd = dv[n][r];
          lsum += __expf(dd * -0.001f);
          lsum += __expf(dd * -0.01f);
          lsum += __expf(dd * -0.1f);
          lsum += __expf(dd * -1.0f);
          lsum += __expf(dd * -10.0f);
          lsum += __expf(dd * -100.0f);
          lsum += __expf(dd * -1000.0f);
        }
    }
  }

  red[tid] = (double)lsum * (double)w;
  __syncthreads();
  #pragma unroll
  for (int s = 128; s > 0; s >>= 1) {
    if (tid < s) red[tid] += red[tid + s];
    __syncthreads();
  }
  if (tid == 0) atomicAdd(acc_out, red[0]);
}

// fp32 diagonal patch: reproduces round-1's sequential-FMA d_ii exactly
__global__ __launch_bounds__(256) void diag_kernel(const float* __restrict__ x,
                                                   const float* __restrict__ y,
                                                   const float* __restrict__ nx,
                                                   const float* __restrict__ ny,
                                                   double* __restrict__ acc_out) {
  __shared__ double red[256];
  int tid = threadIdx.x;
  int idx = (int)blockIdx.x * 256 + tid;   // 0..16383
  int arr = idx >> 13;
  int row = idx & 8191;
  const float* src = (arr ? y : x) + (size_t)row * D;
  float n = (arr ? ny : nx)[row];
  float acc = 0.f;
  #pragma unroll 4
  for (int k4 = 0; k4 < 32; k4++) {
    float4 v = *(const float4*)(src + k4 * 4);
    acc = fmaf(v.x, v.x, acc);
    acc = fmaf(v.y, v.y, acc);
    acc = fmaf(v.z, v.z, acc);
    acc = fmaf(v.w, v.w, acc);
  }
  float d = fmaf(-2.f, acc, n + n);
  d = fmaxf(d, 1e-30f);
  float s = 0.f;
  s += __expf(d * -0.001f);
  s += __expf(d * -0.01f);
  s += __expf(d * -0.1f);
  s += __expf(d * -1.0f);
  s += __expf(d * -10.0f);
  s += __expf(d * -100.0f);
  s += __expf(d * -1000.0f);
  red[tid] = (double)s;
  __syncthreads();
  #pragma unroll
  for (int st = 128; st > 0; st >>= 1) {
    if (tid < st) red[tid] += red[tid + st];
    __syncthreads();
  }
  if (tid == 0) atomicAdd(acc_out, red[0]);
}

__global__ void finalize_kernel(const double* __restrict__ acc,
                                float* __restrict__ out) {
  out[0] = (float)(acc[0] * (1.0 / ((double)N_PTS * (double)N_PTS)));
}

extern "C" void kernel_launch(void* const* d_in, const int* in_sizes, int n_in,
                              void* d_out, int out_size, void* d_ws, size_t ws_size,
                              hipStream_t stream) {
  const float* x = (const float*)d_in[0];
  const float* y = (const float*)d_in[1];
  float* out = (float*)d_out;

  char* ws = (char*)d_ws;
  double* acc = (double*)ws;
  float* nx = (float*)(ws + 256);
  float* ny = nx + N_PTS;

  hipMemsetAsync(acc, 0, sizeof(double), stream);
  hipLaunchKernelGGL(norms_kernel, dim3(256), dim3(256), 0, stream, x, y, nx, ny);
  hipLaunchKernelGGL(mmd_kernel, dim3(NBLK), dim3(256), 0, stream, x, y, nx, ny, acc);
  hipLaunchKernelGGL(diag_kernel, dim3(64), dim3(256), 0, stream, x, y, nx, ny, acc);
  hipLaunchKernelGGL(finalize_kernel, dim3(1), dim3(1), 0, stream, acc, out);
}

// Round 5
// 219.790 us; speedup vs baseline: 2.4497x; 1.2258x over previous
//
#include <hip/hip_runtime.h>

// MMD, 7-gamma Gaussian kernel, x,y: [8192,128] fp32.
// Round 3 design (resubmit x2; both benches were infra failures — never ran):
// pre-convert x,y to MFMA-fragment-ordered bf16 hi|lo arrays (once), then a
// barrier-free, LDS-free Gram kernel loading fragments straight from L2/L3
// into VGPRs. Removes the per-tile fp32->bf16 conversion (was ~65x redundant
// per row and the dominant VALU cost in round 2).
//
// Fragment layout (verified by round-2 pass): for 16x16x32 bf16 MFMA, both
// A and B Gram operands use lane = (row&15) + koct*16, elems [row][ks*32+koct*8+j],
// j=0..7. Array: [rowgrp][ks][lane][8] bf16, rowgrp=row>>4, k'=256 (hi|lo).
// Diagonal patched by exact-fp32 diag_kernel (bit-exactness is load-bearing).

#define N_PTS 8192
#define D 128
#define TILES 64
#define TRI 2080
#define NBLK (2 * TRI + TILES * TILES)

typedef __attribute__((ext_vector_type(8))) short bf16x8;
typedef __attribute__((ext_vector_type(8))) unsigned short u16x8;
typedef __attribute__((ext_vector_type(4))) float f32x4;

__device__ __forceinline__ unsigned short f2bf(float a) {  // RNE
  unsigned u = __float_as_uint(a);
  return (unsigned short)((u + 0x7FFFu + ((u >> 16) & 1u)) >> 16);
}
__device__ __forceinline__ float bf2f(unsigned short b) {
  return __uint_as_float(((unsigned)b) << 16);
}

__global__ __launch_bounds__(256) void norms_kernel(const float* __restrict__ x,
                                                    const float* __restrict__ y,
                                                    float* __restrict__ nx,
                                                    float* __restrict__ ny) {
  int tid = threadIdx.x;
  int g = tid & 3;
  int row = ((int)blockIdx.x & 127) * 64 + (tid >> 2);
  int arr = (int)blockIdx.x >> 7;
  const float* src = arr ? y : x;
  const float4* p = (const float4*)(src + (size_t)row * D) + g;
  float s = 0.f;
  #pragma unroll
  for (int i = 0; i < 8; i++) {
    float4 v = p[i * 4];
    s += v.x * v.x + v.y * v.y + v.z * v.z + v.w * v.w;
  }
  s += __shfl_xor(s, 1);
  s += __shfl_xor(s, 2);
  if (g == 0) (arr ? ny : nx)[row] = s;
}

// x,y -> fragment-ordered bf16 hi|lo arrays. 1 wave per 16-row group.
__global__ __launch_bounds__(256) void convert_kernel(const float* __restrict__ x,
                                                      const float* __restrict__ y,
                                                      unsigned short* __restrict__ xf,
                                                      unsigned short* __restrict__ yf) {
  __shared__ float lds[4][16][132];   // +4 pad
  int tid = threadIdx.x;
  int lane = tid & 63, wv = tid >> 6;
  int grp = (int)blockIdx.x * 4 + wv;        // 0..1023
  int arr = grp >> 9;
  int rowgrp = grp & 511;
  const float* src = (arr ? y : x) + (size_t)rowgrp * 16 * D;
  unsigned short* dst = (arr ? yf : xf) + (size_t)rowgrp * 4096;

  #pragma unroll
  for (int it = 0; it < 8; it++) {
    int slot = it * 64 + lane;               // 0..511 = 16 rows x 32 float4
    int row = slot >> 5, f4 = slot & 31;
    float4 v = *(const float4*)(src + row * D + f4 * 4);
    *(float4*)&lds[wv][row][f4 * 4] = v;
  }
  __syncthreads();

  int row = lane & 15, koct = lane >> 4;
  #pragma unroll
  for (int ks = 0; ks < 8; ks++) {
    int kp = ks * 32 + koct * 8;             // k' in [0,256)
    int kf = kp & 127;                       // source feature base
    bool ishi = kp < 128;
    float v[8];
    *(float4*)&v[0] = *(const float4*)&lds[wv][row][kf];
    *(float4*)&v[4] = *(const float4*)&lds[wv][row][kf + 4];
    u16x8 o;
    #pragma unroll
    for (int j = 0; j < 8; j++) {
      unsigned short h = f2bf(v[j]);
      o[j] = ishi ? h : f2bf(v[j] - bf2f(h));
    }
    *(u16x8*)(dst + ks * 512 + lane * 8) = o;
  }
}

__global__ __launch_bounds__(256) void mmd_frag_kernel(const unsigned short* __restrict__ xf,
                                                       const unsigned short* __restrict__ yf,
                                                       const float* __restrict__ nx,
                                                       const float* __restrict__ ny,
                                                       double* __restrict__ acc_out) {
  __shared__ double red[256];
  int bid = blockIdx.x;
  const unsigned short *Af, *Bf;
  const float *nA, *nB;
  float w;
  int ib, jb;
  bool isdiag = false;
  if (bid < 2 * TRI) {
    int t = (bid < TRI) ? bid : bid - TRI;
    int r = 0;
    while (t >= TILES - r) { t -= TILES - r; r++; }
    ib = r; jb = r + t;
    if (bid < TRI) { Af = xf; Bf = xf; nA = nx; nB = nx; }
    else           { Af = yf; Bf = yf; nA = ny; nB = ny; }
    isdiag = (ib == jb);
    w = isdiag ? 1.0f : 2.0f;
  } else {
    int t = bid - 2 * TRI;
    ib = t >> 6; jb = t & 63;
    Af = xf; Bf = yf; nA = nx; nB = ny;
    w = -2.0f;
  }

  int tid = threadIdx.x;
  int lane = tid & 63;
  int wv = tid >> 6, wm = wv >> 1, wn = wv & 1;
  int r16 = lane & 15, g4 = lane >> 4;

  // rowgrp stride 8192 B, ks stride 1024 B
  const char* Ab = (const char*)Af + (size_t)(ib * 8 + wm * 4) * 8192 + lane * 16;
  const char* Bb = (const char*)Bf + (size_t)(jb * 8 + wn * 4) * 8192 + lane * 16;

  f32x4 acc[4][4];
  #pragma unroll
  for (int m = 0; m < 4; m++)
    #pragma unroll
    for (int n = 0; n < 4; n++) acc[m][n] = (f32x4){0.f, 0.f, 0.f, 0.f};

  #pragma unroll
  for (int ks = 0; ks < 8; ks++) {
    bf16x8 af[4], bfr[4];
    #pragma unroll
    for (int m = 0; m < 4; m++)
      af[m] = *(const bf16x8*)(Ab + m * 8192 + ks * 1024);
    #pragma unroll
    for (int n = 0; n < 4; n++)
      bfr[n] = *(const bf16x8*)(Bb + n * 8192 + ks * 1024);
    #pragma unroll
    for (int m = 0; m < 4; m++)
      #pragma unroll
      for (int n = 0; n < 4; n++)
        acc[m][n] = __builtin_amdgcn_mfma_f32_16x16x32_bf16(af[m], bfr[n], acc[m][n], 0, 0, 0);
  }

  const float* nArow = nA + ib * 128;
  const float* nBrow = nB + jb * 128;
  float nb4[4];
  #pragma unroll
  for (int n = 0; n < 4; n++) nb4[n] = nBrow[wn * 64 + n * 16 + r16];

  float lsum = 0.f;
  #pragma unroll
  for (int m = 0; m < 4; m++) {
    float na4[4];
    #pragma unroll
    for (int r = 0; r < 4; r++) na4[r] = nArow[wm * 64 + m * 16 + g4 * 4 + r];
    float dv[4][4];
    float dmin = 3.0e38f;
    #pragma unroll
    for (int n = 0; n < 4; n++) {
      #pragma unroll
      for (int r = 0; r < 4; r++) {
        float dd = fmaf(-2.f, acc[m][n][r], na4[r] + nb4[n]);
        dd = fmaxf(dd, 1e-30f);
        int rl = wm * 64 + m * 16 + g4 * 4 + r;
        int cl = wn * 64 + n * 16 + r16;
        if (isdiag && rl == cl) dd = 1e30f;   // diag via diag_kernel
        dv[n][r] = dd;
        dmin = fminf(dmin, dd);
      }
    }
    if (__all(dmin > 110.f)) {
      #pragma unroll
      for (int n = 0; n < 4; n++)
        #pragma unroll
        for (int r = 0; r < 4; r++) {
          float dd = dv[n][r];
          lsum += __expf(dd * -0.001f);
          lsum += __expf(dd * -0.01f);
          lsum += __expf(dd * -0.1f);
        }
    } else {
      #pragma unroll
      for (int n = 0; n < 4; n++)
        #pragma unroll
        for (int r = 0; r < 4; r++) {
          float dd = dv[n][r];
          lsum += __expf(dd * -0.001f);
          lsum += __expf(dd * -0.01f);
          lsum += __expf(dd * -0.1f);
          lsum += __expf(dd * -1.0f);
          lsum += __expf(dd * -10.0f);
          lsum += __expf(dd * -100.0f);
          lsum += __expf(dd * -1000.0f);
        }
    }
  }

  red[tid] = (double)lsum * (double)w;
  __syncthreads();
  #pragma unroll
  for (int s = 128; s > 0; s >>= 1) {
    if (tid < s) red[tid] += red[tid + s];
    __syncthreads();
  }
  if (tid == 0) atomicAdd(acc_out, red[0]);
}

// Fallback (round-2 kernel) if ws is too small for fragment arrays.
__global__ __launch_bounds__(256) void mmd_fallback_kernel(const float* __restrict__ X,
                                                           const float* __restrict__ Y,
                                                           const float* __restrict__ nx,
                                                           const float* __restrict__ ny,
                                                           double* __restrict__ acc_out) {
  __shared__ unsigned short As[128 * 64];
  __shared__ unsigned short Bs[128 * 64];
  __shared__ double red[256];
  int bid = blockIdx.x;
  const float *A, *B, *nA, *nB;
  float w;
  int ib, jb;
  bool isdiag = false;
  if (bid < 2 * TRI) {
    int t = (bid < TRI) ? bid : bid - TRI;
    int r = 0;
    while (t >= TILES - r) { t -= TILES - r; r++; }
    ib = r; jb = r + t;
    if (bid < TRI) { A = X; B = X; nA = nx; nB = nx; }
    else           { A = Y; B = Y; nA = ny; nB = ny; }
    isdiag = (ib == jb);
    w = isdiag ? 1.0f : 2.0f;
  } else {
    int t = bid - 2 * TRI;
    ib = t >> 6; jb = t & 63;
    A = X; B = Y; nA = nx; nB = ny;
    w = -2.0f;
  }
  int tid = threadIdx.x;
  int lane = tid & 63;
  int wv = tid >> 6, wm = wv >> 1, wn = wv & 1;
  int r16 = lane & 15, g4 = lane >> 4;
  const float* Ab = A + (size_t)ib * 128 * D;
  const float* Bb = B + (size_t)jb * 128 * D;
  f32x4 acc[4][4];
  #pragma unroll
  for (int m = 0; m < 4; m++)
    #pragma unroll
    for (int n = 0; n < 4; n++) acc[m][n] = (f32x4){0.f, 0.f, 0.f, 0.f};
  #pragma unroll 1
  for (int kc = 0; kc < 4; kc++) {
    int k0f = (kc & 1) * 64;
    bool ishi = (kc < 2);
    __syncthreads();
    #pragma unroll
    for (int s = 0; s < 4; s++) {
      int slot = tid + s * 256;
      int row = slot >> 3;
      int k2 = (slot & 7) * 8;
      const float* pa = Ab + row * D + k0f + k2;
      const float* pb = Bb + row * D + k0f + k2;
      float4 a0 = *(const float4*)pa;
      float4 a1 = *(const float4*)(pa + 4);
      float4 b0 = *(const float4*)pb;
      float4 b1 = *(const float4*)(pb + 4);
      float av[8] = {a0.x, a0.y, a0.z, a0.w, a1.x, a1.y, a1.z, a1.w};
      float bv[8] = {b0.x, b0.y, b0.z, b0.w, b1.x, b1.y, b1.z, b1.w};
      u16x8 ua, ub;
      #pragma unroll
      for (int j = 0; j < 8; j++) {
        unsigned short ha = f2bf(av[j]);
        unsigned short hb = f2bf(bv[j]);
        if (ishi) { ua[j] = (short)ha; ub[j] = (short)hb; }
        else {
          ua[j] = f2bf(av[j] - bf2f(ha));
          ub[j] = f2bf(bv[j] - bf2f(hb));
        }
      }
      int boff = row * 128 + ((k2 * 2) ^ ((row & 7) << 4));
      *(u16x8*)((char*)As + boff) = ua;
      *(u16x8*)((char*)Bs + boff) = ub;
    }
    __syncthreads();
    #pragma unroll
    for (int ks = 0; ks < 2; ks++) {
      bf16x8 af[4], bfr[4];
      int kb = ks * 64 + g4 * 16;
      #pragma unroll
      for (int m = 0; m < 4; m++) {
        int row = wm * 64 + m * 16 + r16;
        af[m] = *(const bf16x8*)((const char*)As + row * 128 + (kb ^ ((row & 7) << 4)));
      }
      #pragma unroll
      for (int n = 0; n < 4; n++) {
        int row = wn * 64 + n * 16 + r16;
        bfr[n] = *(const bf16x8*)((const char*)Bs + row * 128 + (kb ^ ((row & 7) << 4)));
      }
      #pragma unroll
      for (int m = 0; m < 4; m++)
        #pragma unroll
        for (int n = 0; n < 4; n++)
          acc[m][n] = __builtin_amdgcn_mfma_f32_16x16x32_bf16(af[m], bfr[n], acc[m][n], 0, 0, 0);
    }
  }
  const float* nArow = nA + ib * 128;
  const float* nBrow = nB + jb * 128;
  float nb4[4];
  #pragma unroll
  for (int n = 0; n < 4; n++) nb4[n] = nBrow[wn * 64 + n * 16 + r16];
  float lsum = 0.f;
  #pragma unroll
  for (int m = 0; m < 4; m++) {
    float na4[4];
    #pragma unroll
    for (int r = 0; r < 4; r++) na4[r] = nArow[wm * 64 + m * 16 + g4 * 4 + r];
    float dv[4][4];
    float dmin = 3.0e38f;
    #pragma unroll
    for (int n = 0; n < 4; n++) {
      #pragma unroll
      for (int r = 0; r < 4; r++) {
        float dd = fmaf(-2.f, acc[m][n][r], na4[r] + nb4[n]);
        dd = fmaxf(dd, 1e-30f);
        int rl = wm * 64 + m * 16 + g4 * 4 + r;
        int cl = wn * 64 + n * 16 + r16;
        if (isdiag && rl == cl) dd = 1e30f;
        dv[n][r] = dd;
        dmin = fminf(dmin, dd);
      }
    }
    if (__all(dmin > 110.f)) {
      #pragma unroll
      for (int n = 0; n < 4; n++)
        #pragma unroll
        for (int r = 0; r < 4; r++) {
          float dd = dv[n][r];
          lsum += __expf(dd * -0.001f);
          lsum += __expf(dd * -0.01f);
          lsum += __expf(dd * -0.1f);
        }
    } else {
      #pragma unroll
      for (int n = 0; n < 4; n++)
        #pragma unroll
        for (int r = 0; r < 4; r++) {
          float dd = dv[n][r];
          lsum += __expf(dd * -0.001f);
          lsum += __expf(dd * -0.01f);
          lsum += __expf(dd * -0.1f);
          lsum += __expf(dd * -1.0f);
          lsum += __expf(dd * -10.0f);
          lsum += __expf(dd * -100.0f);
          lsum += __expf(dd * -1000.0f);
        }
    }
  }
  red[tid] = (double)lsum * (double)w;
  __syncthreads();
  #pragma unroll
  for (int s = 128; s > 0; s >>= 1) {
    if (tid < s) red[tid] += red[tid + s];
    __syncthreads();
  }
  if (tid == 0) atomicAdd(acc_out, red[0]);
}

__global__ __launch_bounds__(256) void diag_kernel(const float* __restrict__ x,
                                                   const float* __restrict__ y,
                                                   const float* __restrict__ nx,
                                                   const float* __restrict__ ny,
                                                   double* __restrict__ acc_out) {
  __shared__ double red[256];
  int tid = threadIdx.x;
  int idx = (int)blockIdx.x * 256 + tid;
  int arr = idx >> 13;
  int row = idx & 8191;
  const float* src = (arr ? y : x) + (size_t)row * D;
  float n = (arr ? ny : nx)[row];
  float acc = 0.f;
  #pragma unroll 4
  for (int k4 = 0; k4 < 32; k4++) {
    float4 v = *(const float4*)(src + k4 * 4);
    acc = fmaf(v.x, v.x, acc);
    acc = fmaf(v.y, v.y, acc);
    acc = fmaf(v.z, v.z, acc);
    acc = fmaf(v.w, v.w, acc);
  }
  float d = fmaf(-2.f, acc, n + n);
  d = fmaxf(d, 1e-30f);
  float s = 0.f;
  s += __expf(d * -0.001f);
  s += __expf(d * -0.01f);
  s += __expf(d * -0.1f);
  s += __expf(d * -1.0f);
  s += __expf(d * -10.0f);
  s += __expf(d * -100.0f);
  s += __expf(d * -1000.0f);
  red[tid] = (double)s;
  __syncthreads();
  #pragma unroll
  for (int st = 128; st > 0; st >>= 1) {
    if (tid < st) red[tid] += red[tid + st];
    __syncthreads();
  }
  if (tid == 0) atomicAdd(acc_out, red[0]);
}

__global__ void finalize_kernel(const double* __restrict__ acc,
                                float* __restrict__ out) {
  out[0] = (float)(acc[0] * (1.0 / ((double)N_PTS * (double)N_PTS)));
}

extern "C" void kernel_launch(void* const* d_in, const int* in_sizes, int n_in,
                              void* d_out, int out_size, void* d_ws, size_t ws_size,
                              hipStream_t stream) {
  const float* x = (const float*)d_in[0];
  const float* y = (const float*)d_in[1];
  float* out = (float*)d_out;

  char* ws = (char*)d_ws;
  double* acc = (double*)ws;                       // 8 B
  float* nx = (float*)(ws + 4096);                 // 8192 f
  float* ny = (float*)(ws + 36864);                // 8192 f
  const size_t FRAG_OFF = 69632;
  const size_t FRAG_SZ = 4194304;                  // 4 MB each
  const size_t NEED = FRAG_OFF + 2 * FRAG_SZ;

  hipMemsetAsync(acc, 0, sizeof(double), stream);
  hipLaunchKernelGGL(norms_kernel, dim3(256), dim3(256), 0, stream, x, y, nx, ny);
  if (ws_size >= NEED) {
    unsigned short* xf = (unsigned short*)(ws + FRAG_OFF);
    unsigned short* yf = (unsigned short*)(ws + FRAG_OFF + FRAG_SZ);
    hipLaunchKernelGGL(convert_kernel, dim3(256), dim3(256), 0, stream, x, y, xf, yf);
    hipLaunchKernelGGL(mmd_frag_kernel, dim3(NBLK), dim3(256), 0, stream, xf, yf, nx, ny, acc);
  } else {
    hipLaunchKernelGGL(mmd_fallback_kernel, dim3(NBLK), dim3(256), 0, stream, x, y, nx, ny, acc);
  }
  hipLaunchKernelGGL(diag_kernel, dim3(64), dim3(256), 0, stream, x, y, nx, ny, acc);
  hipLaunchKernelGGL(finalize_kernel, dim3(1), dim3(1), 0, stream, acc, out);
}

// Round 6
// 217.689 us; speedup vs baseline: 2.4733x; 1.0096x over previous
//
#include <hip/hip_runtime.h>

// MMD, 7-gamma Gaussian kernel, x,y: [8192,128] fp32.
// Round 6: 256x256 tiles + LDS staging of pre-converted bf16 hi|lo fragments
// via global_load_lds (width 16), 2-buffer prefetch, 8 waves/block.
// Round-5 evidence: LDS-free version was latency/L2-bound (MfmaUtil 17%,
// VALUBusy 50%, occupancy 21%) from 16 B/pair refetch. This cuts traffic to
// 4 B/pair and pipelines staging under MFMA.
// Fragment array layout (verified rounds 2/5): [rowgrp][ks][lane][8] bf16,
// rowgrp stride 4096 ushorts, ks stride 512; serves both A and B operands.
// Diagonal patched by exact-fp32 diag_kernel (bit-exact vs round-1 baseline).

#define N_PTS 8192
#define D 128
#define T2 32                         // 8192/256
#define TRI2 528                      // 32*33/2
#define NBLK2 (2 * TRI2 + T2 * T2)    // 2080
#define TILES 64
#define TRI 2080
#define NBLK (2 * TRI + TILES * TILES)
#define CH_US 16384                   // ushorts per 32KB chunk buffer

typedef __attribute__((ext_vector_type(8))) short bf16x8;
typedef __attribute__((ext_vector_type(8))) unsigned short u16x8;
typedef __attribute__((ext_vector_type(4))) float f32x4;

__device__ __forceinline__ unsigned short f2bf(float a) {  // RNE
  unsigned u = __float_as_uint(a);
  return (unsigned short)((u + 0x7FFFu + ((u >> 16) & 1u)) >> 16);
}
__device__ __forceinline__ float bf2f(unsigned short b) {
  return __uint_as_float(((unsigned)b) << 16);
}

__global__ __launch_bounds__(256) void norms_kernel(const float* __restrict__ x,
                                                    const float* __restrict__ y,
                                                    float* __restrict__ nx,
                                                    float* __restrict__ ny) {
  int tid = threadIdx.x;
  int g = tid & 3;
  int row = ((int)blockIdx.x & 127) * 64 + (tid >> 2);
  int arr = (int)blockIdx.x >> 7;
  const float* src = arr ? y : x;
  const float4* p = (const float4*)(src + (size_t)row * D) + g;
  float s = 0.f;
  #pragma unroll
  for (int i = 0; i < 8; i++) {
    float4 v = p[i * 4];
    s += v.x * v.x + v.y * v.y + v.z * v.z + v.w * v.w;
  }
  s += __shfl_xor(s, 1);
  s += __shfl_xor(s, 2);
  if (g == 0) (arr ? ny : nx)[row] = s;
}

// x,y -> fragment-ordered bf16 hi|lo arrays. 1 wave per 16-row group.
__global__ __launch_bounds__(256) void convert_kernel(const float* __restrict__ x,
                                                      const float* __restrict__ y,
                                                      unsigned short* __restrict__ xf,
                                                      unsigned short* __restrict__ yf) {
  __shared__ float lds[4][16][132];
  int tid = threadIdx.x;
  int lane = tid & 63, wv = tid >> 6;
  int grp = (int)blockIdx.x * 4 + wv;
  int arr = grp >> 9;
  int rowgrp = grp & 511;
  const float* src = (arr ? y : x) + (size_t)rowgrp * 16 * D;
  unsigned short* dst = (arr ? yf : xf) + (size_t)rowgrp * 4096;

  #pragma unroll
  for (int it = 0; it < 8; it++) {
    int slot = it * 64 + lane;
    int row = slot >> 5, f4 = slot & 31;
    float4 v = *(const float4*)(src + row * D + f4 * 4);
    *(float4*)&lds[wv][row][f4 * 4] = v;
  }
  __syncthreads();

  int row = lane & 15, koct = lane >> 4;
  #pragma unroll
  for (int ks = 0; ks < 8; ks++) {
    int kp = ks * 32 + koct * 8;
    int kf = kp & 127;
    bool ishi = kp < 128;
    float v[8];
    *(float4*)&v[0] = *(const float4*)&lds[wv][row][kf];
    *(float4*)&v[4] = *(const float4*)&lds[wv][row][kf + 4];
    u16x8 o;
    #pragma unroll
    for (int j = 0; j < 8; j++) {
      unsigned short h = f2bf(v[j]);
      o[j] = ishi ? h : f2bf(v[j] - bf2f(h));
    }
    *(u16x8*)(dst + ks * 512 + lane * 8) = o;
  }
}

// stage one K'=64 chunk (2 ks-slices) of a 256-row tile: 32 A + 32 B slots of
// 1024 B, 8 slots per wave, global_load_lds width 16 (linear lane order).
__device__ __forceinline__ void stage_chunk(const unsigned short* __restrict__ Afrag,
                                            const unsigned short* __restrict__ Bfrag,
                                            unsigned short* As, unsigned short* Bs,
                                            int c, int wv, int lane) {
  #pragma unroll
  for (int i = 0; i < 4; i++) {
    int s = wv * 4 + i;
    int rg = s >> 1, ksl = s & 1;
    const unsigned short* ga = Afrag + (size_t)rg * 4096 + (2 * c + ksl) * 512 + lane * 8;
    const unsigned short* gb = Bfrag + (size_t)rg * 4096 + (2 * c + ksl) * 512 + lane * 8;
    __builtin_amdgcn_global_load_lds(
        (const __attribute__((address_space(1))) void*)ga,
        (__attribute__((address_space(3))) void*)(As + s * 512), 16, 0, 0);
    __builtin_amdgcn_global_load_lds(
        (const __attribute__((address_space(1))) void*)gb,
        (__attribute__((address_space(3))) void*)(Bs + s * 512), 16, 0, 0);
  }
}

__global__ __launch_bounds__(512, 2) void mmd_tile256_kernel(
    const unsigned short* __restrict__ xf, const unsigned short* __restrict__ yf,
    const float* __restrict__ nx, const float* __restrict__ ny,
    double* __restrict__ acc_out) {
  extern __shared__ char smem[];
  unsigned short* As = (unsigned short*)smem;             // [2][CH_US]
  unsigned short* Bs = (unsigned short*)(smem + 65536);   // [2][CH_US]
  double* red = (double*)(smem + 131072);                 // [8]

  int bid = blockIdx.x;
  const unsigned short *Af, *Bf;
  const float *nA, *nB;
  float w;
  int ib, jb;
  bool isdiag = false;
  if (bid < 2 * TRI2) {
    int t = (bid < TRI2) ? bid : bid - TRI2;
    int r = 0;
    while (t >= T2 - r) { t -= T2 - r; r++; }   // upper-tri decode
    ib = r; jb = r + t;
    if (bid < TRI2) { Af = xf; Bf = xf; nA = nx; nB = nx; }
    else            { Af = yf; Bf = yf; nA = ny; nB = ny; }
    isdiag = (ib == jb);
    w = isdiag ? 1.0f : 2.0f;
  } else {
    int t = bid - 2 * TRI2;
    ib = t >> 5; jb = t & 31;
    Af = xf; Bf = yf; nA = nx; nB = ny;
    w = -2.0f;
  }

  int tid = threadIdx.x;
  int lane = tid & 63, wv = tid >> 6;
  int wm = wv >> 2, wn = wv & 3;          // 2x4 waves; per-wave 128x64 out
  int r16 = lane & 15, g4 = lane >> 4;

  const unsigned short* Afrag = Af + (size_t)(ib * 16) * 4096;
  const unsigned short* Bfrag = Bf + (size_t)(jb * 16) * 4096;

  f32x4 acc[8][4];
  #pragma unroll
  for (int m = 0; m < 8; m++)
    #pragma unroll
    for (int n = 0; n < 4; n++) acc[m][n] = (f32x4){0.f, 0.f, 0.f, 0.f};

  stage_chunk(Afrag, Bfrag, As, Bs, 0, wv, lane);
  __syncthreads();

  #pragma unroll
  for (int c = 0; c < 4; c++) {
    if (c < 3)
      stage_chunk(Afrag, Bfrag, As + ((c + 1) & 1) * CH_US,
                  Bs + ((c + 1) & 1) * CH_US, c + 1, wv, lane);
    const unsigned short* Ab = As + (c & 1) * CH_US;
    const unsigned short* Bb = Bs + (c & 1) * CH_US;
    #pragma unroll
    for (int ksl = 0; ksl < 2; ksl++) {
      bf16x8 a[8], b[4];
      #pragma unroll
      for (int m = 0; m < 8; m++)
        a[m] = *(const bf16x8*)(Ab + ((wm * 8 + m) * 2 + ksl) * 512 + lane * 8);
      #pragma unroll
      for (int n = 0; n < 4; n++)
        b[n] = *(const bf16x8*)(Bb + ((wn * 4 + n) * 2 + ksl) * 512 + lane * 8);
      #pragma unroll
      for (int m = 0; m < 8; m++)
        #pragma unroll
        for (int n = 0; n < 4; n++)
          acc[m][n] = __builtin_amdgcn_mfma_f32_16x16x32_bf16(a[m], b[n], acc[m][n], 0, 0, 0);
    }
    __syncthreads();   // drains staging vmcnt + protects buffer swap
  }

  // epilogue: d = n_i + n_j - 2*dot; C/D: col=lane&15, row=(lane>>4)*4+reg
  const float* nArow = nA + ib * 256;
  const float* nBrow = nB + jb * 256;
  float nb4[4];
  #pragma unroll
  for (int n = 0; n < 4; n++) nb4[n] = nBrow[wn * 64 + n * 16 + r16];

  float lsum = 0.f;
  #pragma unroll
  for (int m = 0; m < 8; m++) {
    float na4[4];
    #pragma unroll
    for (int r = 0; r < 4; r++) na4[r] = nArow[wm * 128 + m * 16 + g4 * 4 + r];
    float dv[4][4];
    float dmin = 3.0e38f;
    #pragma unroll
    for (int n = 0; n < 4; n++) {
      #pragma unroll
      for (int r = 0; r < 4; r++) {
        float dd = fmaf(-2.f, acc[m][n][r], na4[r] + nb4[n]);
        dd = fmaxf(dd, 1e-30f);
        int rl = wm * 128 + m * 16 + g4 * 4 + r;
        int cl = wn * 64 + n * 16 + r16;
        if (isdiag && rl == cl) dd = 1e30f;   // diag via diag_kernel; exp->0
        dv[n][r] = dd;
        dmin = fminf(dmin, dd);
      }
    }
    if (__all(dmin > 110.f)) {
      // exp(-g*d) == 0.0f exactly for g>=1 when d>110 (also 0 in reference)
      #pragma unroll
      for (int n = 0; n < 4; n++)
        #pragma unroll
        for (int r = 0; r < 4; r++) {
          float dd = dv[n][r];
          lsum += __expf(dd * -0.001f);
          lsum += __expf(dd * -0.01f);
          lsum += __expf(dd * -0.1f);
        }
    } else {
      #pragma unroll
      for (int n = 0; n < 4; n++)
        #pragma unroll
        for (int r = 0; r < 4; r++) {
          float dd = dv[n][r];
          lsum += __expf(dd * -0.001f);
          lsum += __expf(dd * -0.01f);
          lsum += __expf(dd * -0.1f);
          lsum += __expf(dd * -1.0f);
          lsum += __expf(dd * -10.0f);
          lsum += __expf(dd * -100.0f);
          lsum += __expf(dd * -1000.0f);
        }
    }
  }

  double v = (double)lsum * (double)w;
  v += __shfl_xor(v, 32);
  v += __shfl_xor(v, 16);
  v += __shfl_xor(v, 8);
  v += __shfl_xor(v, 4);
  v += __shfl_xor(v, 2);
  v += __shfl_xor(v, 1);
  if (lane == 0) red[wv] = v;
  __syncthreads();
  if (tid == 0) {
    double s = 0.0;
    #pragma unroll
    for (int i = 0; i < 8; i++) s += red[i];
    atomicAdd(acc_out, s);
  }
}

// Fallback (round-2 kernel, no frag arrays) if ws is too small.
__global__ __launch_bounds__(256) void mmd_fallback_kernel(const float* __restrict__ X,
                                                           const float* __restrict__ Y,
                                                           const float* __restrict__ nx,
                                                           const float* __restrict__ ny,
                                                           double* __restrict__ acc_out) {
  __shared__ unsigned short As[128 * 64];
  __shared__ unsigned short Bs[128 * 64];
  __shared__ double red[256];
  int bid = blockIdx.x;
  const float *A, *B, *nA, *nB;
  float w;
  int ib, jb;
  bool isdiag = false;
  if (bid < 2 * TRI) {
    int t = (bid < TRI) ? bid : bid - TRI;
    int r = 0;
    while (t >= TILES - r) { t -= TILES - r; r++; }
    ib = r; jb = r + t;
    if (bid < TRI) { A = X; B = X; nA = nx; nB = nx; }
    else           { A = Y; B = Y; nA = ny; nB = ny; }
    isdiag = (ib == jb);
    w = isdiag ? 1.0f : 2.0f;
  } else {
    int t = bid - 2 * TRI;
    ib = t >> 6; jb = t & 63;
    A = X; B = Y; nA = nx; nB = ny;
    w = -2.0f;
  }
  int tid = threadIdx.x;
  int lane = tid & 63;
  int wv = tid >> 6, wm = wv >> 1, wn = wv & 1;
  int r16 = lane & 15, g4 = lane >> 4;
  const float* Ab = A + (size_t)ib * 128 * D;
  const float* Bb = B + (size_t)jb * 128 * D;
  f32x4 acc[4][4];
  #pragma unroll
  for (int m = 0; m < 4; m++)
    #pragma unroll
    for (int n = 0; n < 4; n++) acc[m][n] = (f32x4){0.f, 0.f, 0.f, 0.f};
  #pragma unroll 1
  for (int kc = 0; kc < 4; kc++) {
    int k0f = (kc & 1) * 64;
    bool ishi = (kc < 2);
    __syncthreads();
    #pragma unroll
    for (int s = 0; s < 4; s++) {
      int slot = tid + s * 256;
      int row = slot >> 3;
      int k2 = (slot & 7) * 8;
      const float* pa = Ab + row * D + k0f + k2;
      const float* pb = Bb + row * D + k0f + k2;
      float4 a0 = *(const float4*)pa;
      float4 a1 = *(const float4*)(pa + 4);
      float4 b0 = *(const float4*)pb;
      float4 b1 = *(const float4*)(pb + 4);
      float av[8] = {a0.x, a0.y, a0.z, a0.w, a1.x, a1.y, a1.z, a1.w};
      float bv[8] = {b0.x, b0.y, b0.z, b0.w, b1.x, b1.y, b1.z, b1.w};
      u16x8 ua, ub;
      #pragma unroll
      for (int j = 0; j < 8; j++) {
        unsigned short ha = f2bf(av[j]);
        unsigned short hb = f2bf(bv[j]);
        if (ishi) { ua[j] = (short)ha; ub[j] = (short)hb; }
        else {
          ua[j] = f2bf(av[j] - bf2f(ha));
          ub[j] = f2bf(bv[j] - bf2f(hb));
        }
      }
      int boff = row * 128 + ((k2 * 2) ^ ((row & 7) << 4));
      *(u16x8*)((char*)As + boff) = ua;
      *(u16x8*)((char*)Bs + boff) = ub;
    }
    __syncthreads();
    #pragma unroll
    for (int ks = 0; ks < 2; ks++) {
      bf16x8 af[4], bfr[4];
      int kb = ks * 64 + g4 * 16;
      #pragma unroll
      for (int m = 0; m < 4; m++) {
        int row = wm * 64 + m * 16 + r16;
        af[m] = *(const bf16x8*)((const char*)As + row * 128 + (kb ^ ((row & 7) << 4)));
      }
      #pragma unroll
      for (int n = 0; n < 4; n++) {
        int row = wn * 64 + n * 16 + r16;
        bfr[n] = *(const bf16x8*)((const char*)Bs + row * 128 + (kb ^ ((row & 7) << 4)));
      }
      #pragma unroll
      for (int m = 0; m < 4; m++)
        #pragma unroll
        for (int n = 0; n < 4; n++)
          acc[m][n] = __builtin_amdgcn_mfma_f32_16x16x32_bf16(af[m], bfr[n], acc[m][n], 0, 0, 0);
    }
  }
  const float* nArow = nA + ib * 128;
  const float* nBrow = nB + jb * 128;
  float nb4[4];
  #pragma unroll
  for (int n = 0; n < 4; n++) nb4[n] = nBrow[wn * 64 + n * 16 + r16];
  float lsum = 0.f;
  #pragma unroll
  for (int m = 0; m < 4; m++) {
    float na4[4];
    #pragma unroll
    for (int r = 0; r < 4; r++) na4[r] = nArow[wm * 64 + m * 16 + g4 * 4 + r];
    float dv[4][4];
    float dmin = 3.0e38f;
    #pragma unroll
    for (int n = 0; n < 4; n++) {
      #pragma unroll
      for (int r = 0; r < 4; r++) {
        float dd = fmaf(-2.f, acc[m][n][r], na4[r] + nb4[n]);
        dd = fmaxf(dd, 1e-30f);
        int rl = wm * 64 + m * 16 + g4 * 4 + r;
        int cl = wn * 64 + n * 16 + r16;
        if (isdiag && rl == cl) dd = 1e30f;
        dv[n][r] = dd;
        dmin = fminf(dmin, dd);
      }
    }
    if (__all(dmin > 110.f)) {
      #pragma unroll
      for (int n = 0; n < 4; n++)
        #pragma unroll
        for (int r = 0; r < 4; r++) {
          float dd = dv[n][r];
          lsum += __expf(dd * -0.001f);
          lsum += __expf(dd * -0.01f);
          lsum += __expf(dd * -0.1f);
        }
    } else {
      #pragma unroll
      for (int n = 0; n < 4; n++)
        #pragma unroll
        for (int r = 0; r < 4; r++) {
          float dd = dv[n][r];
          lsum += __expf(dd * -0.001f);
          lsum += __expf(dd * -0.01f);
          lsum += __expf(dd * -0.1f);
          lsum += __expf(dd * -1.0f);
          lsum += __expf(dd * -10.0f);
          lsum += __expf(dd * -100.0f);
          lsum += __expf(dd * -1000.0f);
        }
    }
  }
  red[tid] = (double)lsum * (double)w;
  __syncthreads();
  #pragma unroll
  for (int s = 128; s > 0; s >>= 1) {
    if (tid < s) red[tid] += red[tid + s];
    __syncthreads();
  }
  if (tid == 0) atomicAdd(acc_out, red[0]);
}

__global__ __launch_bounds__(256) void diag_kernel(const float* __restrict__ x,
                                                   const float* __restrict__ y,
                                                   const float* __restrict__ nx,
                                                   const float* __restrict__ ny,
                                                   double* __restrict__ acc_out) {
  __shared__ double red[256];
  int tid = threadIdx.x;
  int idx = (int)blockIdx.x * 256 + tid;
  int arr = idx >> 13;
  int row = idx & 8191;
  const float* src = (arr ? y : x) + (size_t)row * D;
  float n = (arr ? ny : nx)[row];
  float acc = 0.f;
  #pragma unroll 4
  for (int k4 = 0; k4 < 32; k4++) {
    float4 v = *(const float4*)(src + k4 * 4);
    acc = fmaf(v.x, v.x, acc);
    acc = fmaf(v.y, v.y, acc);
    acc = fmaf(v.z, v.z, acc);
    acc = fmaf(v.w, v.w, acc);
  }
  float d = fmaf(-2.f, acc, n + n);
  d = fmaxf(d, 1e-30f);
  float s = 0.f;
  s += __expf(d * -0.001f);
  s += __expf(d * -0.01f);
  s += __expf(d * -0.1f);
  s += __expf(d * -1.0f);
  s += __expf(d * -10.0f);
  s += __expf(d * -100.0f);
  s += __expf(d * -1000.0f);
  red[tid] = (double)s;
  __syncthreads();
  #pragma unroll
  for (int st = 128; st > 0; st >>= 1) {
    if (tid < st) red[tid] += red[tid + st];
    __syncthreads();
  }
  if (tid == 0) atomicAdd(acc_out, red[0]);
}

__global__ void finalize_kernel(const double* __restrict__ acc,
                                float* __restrict__ out) {
  out[0] = (float)(acc[0] * (1.0 / ((double)N_PTS * (double)N_PTS)));
}

extern "C" void kernel_launch(void* const* d_in, const int* in_sizes, int n_in,
                              void* d_out, int out_size, void* d_ws, size_t ws_size,
                              hipStream_t stream) {
  const float* x = (const float*)d_in[0];
  const float* y = (const float*)d_in[1];
  float* out = (float*)d_out;

  char* ws = (char*)d_ws;
  double* acc = (double*)ws;                       // 8 B
  float* nx = (float*)(ws + 4096);                 // 8192 f
  float* ny = (float*)(ws + 36864);                // 8192 f
  const size_t FRAG_OFF = 69632;
  const size_t FRAG_SZ = 4194304;                  // 4 MB each
  const size_t NEED = FRAG_OFF + 2 * FRAG_SZ;      // same as round 5 (proven fit)

  hipMemsetAsync(acc, 0, sizeof(double), stream);
  hipLaunchKernelGGL(norms_kernel, dim3(256), dim3(256), 0, stream, x, y, nx, ny);
  if (ws_size >= NEED) {
    unsigned short* xf = (unsigned short*)(ws + FRAG_OFF);
    unsigned short* yf = (unsigned short*)(ws + FRAG_OFF + FRAG_SZ);
    hipLaunchKernelGGL(convert_kernel, dim3(256), dim3(256), 0, stream, x, y, xf, yf);
    hipLaunchKernelGGL(mmd_tile256_kernel, dim3(NBLK2), dim3(512), 131136, stream,
                       xf, yf, nx, ny, acc);
  } else {
    hipLaunchKernelGGL(mmd_fallback_kernel, dim3(NBLK), dim3(256), 0, stream, x, y, nx, ny, acc);
  }
  hipLaunchKernelGGL(diag_kernel, dim3(64), dim3(256), 0, stream, x, y, nx, ny, acc);
  hipLaunchKernelGGL(finalize_kernel, dim3(1), dim3(1), 0, stream, acc, out);
}

// Round 9
// 216.843 us; speedup vs baseline: 2.4830x; 1.0039x over previous
//
#include <hip/hip_runtime.h>

// MMD, 7-gamma Gaussian kernel, x,y: [8192,128] fp32.
// Round 7 design (resubmit x2; rounds 7/8 benches were GPUAcquisitionTimeout —
// kernel never ran): 128x128 tiles, 4 waves, K'=32 chunks staged via
// global_load_lds, double-buffered, 32 KB LDS/block -> ~4 blocks/CU.
// Round-6 evidence: 256x256 tile (131 KB LDS, 1 block/CU) serialized on the
// per-chunk barrier vmcnt drain (occ 20%, both pipes <50%). Small blocks
// restore cross-block overlap (m114) so barrier drains hide under other
// blocks' compute.
// Fragment array layout (verified rounds 2/5/6): [rowgrp][ks][lane][8] bf16,
// rowgrp stride 4096 ushorts, ks stride 512; serves both A and B operands.
// Numerics bit-identical to rounds 5/6 (ks 0..7 in-order accumulation).
// Diagonal patched by exact-fp32 diag_kernel (bit-exact vs round-1 baseline).

#define N_PTS 8192
#define D 128
#define TILES 64
#define TRI 2080
#define NBLK (2 * TRI + TILES * TILES)

typedef __attribute__((ext_vector_type(8))) short bf16x8;
typedef __attribute__((ext_vector_type(8))) unsigned short u16x8;
typedef __attribute__((ext_vector_type(4))) float f32x4;

__device__ __forceinline__ unsigned short f2bf(float a) {  // RNE
  unsigned u = __float_as_uint(a);
  return (unsigned short)((u + 0x7FFFu + ((u >> 16) & 1u)) >> 16);
}
__device__ __forceinline__ float bf2f(unsigned short b) {
  return __uint_as_float(((unsigned)b) << 16);
}

__global__ __launch_bounds__(256) void norms_kernel(const float* __restrict__ x,
                                                    const float* __restrict__ y,
                                                    float* __restrict__ nx,
                                                    float* __restrict__ ny) {
  int tid = threadIdx.x;
  int g = tid & 3;
  int row = ((int)blockIdx.x & 127) * 64 + (tid >> 2);
  int arr = (int)blockIdx.x >> 7;
  const float* src = arr ? y : x;
  const float4* p = (const float4*)(src + (size_t)row * D) + g;
  float s = 0.f;
  #pragma unroll
  for (int i = 0; i < 8; i++) {
    float4 v = p[i * 4];
    s += v.x * v.x + v.y * v.y + v.z * v.z + v.w * v.w;
  }
  s += __shfl_xor(s, 1);
  s += __shfl_xor(s, 2);
  if (g == 0) (arr ? ny : nx)[row] = s;
}

// x,y -> fragment-ordered bf16 hi|lo arrays. 1 wave per 16-row group.
__global__ __launch_bounds__(256) void convert_kernel(const float* __restrict__ x,
                                                      const float* __restrict__ y,
                                                      unsigned short* __restrict__ xf,
                                                      unsigned short* __restrict__ yf) {
  __shared__ float lds[4][16][132];
  int tid = threadIdx.x;
  int lane = tid & 63, wv = tid >> 6;
  int grp = (int)blockIdx.x * 4 + wv;
  int arr = grp >> 9;
  int rowgrp = grp & 511;
  const float* src = (arr ? y : x) + (size_t)rowgrp * 16 * D;
  unsigned short* dst = (arr ? yf : xf) + (size_t)rowgrp * 4096;

  #pragma unroll
  for (int it = 0; it < 8; it++) {
    int slot = it * 64 + lane;
    int row = slot >> 5, f4 = slot & 31;
    float4 v = *(const float4*)(src + row * D + f4 * 4);
    *(float4*)&lds[wv][row][f4 * 4] = v;
  }
  __syncthreads();

  int row = lane & 15, koct = lane >> 4;
  #pragma unroll
  for (int ks = 0; ks < 8; ks++) {
    int kp = ks * 32 + koct * 8;
    int kf = kp & 127;
    bool ishi = kp < 128;
    float v[8];
    *(float4*)&v[0] = *(const float4*)&lds[wv][row][kf];
    *(float4*)&v[4] = *(const float4*)&lds[wv][row][kf + 4];
    u16x8 o;
    #pragma unroll
    for (int j = 0; j < 8; j++) {
      unsigned short h = f2bf(v[j]);
      o[j] = ishi ? h : f2bf(v[j] - bf2f(h));
    }
    *(u16x8*)(dst + ks * 512 + lane * 8) = o;
  }
}

__global__ __launch_bounds__(256, 4) void mmd_tile128_kernel(
    const unsigned short* __restrict__ xf, const unsigned short* __restrict__ yf,
    const float* __restrict__ nx, const float* __restrict__ ny,
    double* __restrict__ acc_out) {
  __shared__ unsigned short As[2][4096];   // [buf][rg(8)*512], 8 KB each
  __shared__ unsigned short Bs[2][4096];
  __shared__ double red[4];

  int bid = blockIdx.x;
  const unsigned short *Af, *Bf;
  const float *nA, *nB;
  float w;
  int ib, jb;
  bool isdiag = false;
  if (bid < 2 * TRI) {
    int t = (bid < TRI) ? bid : bid - TRI;
    int r = 0;
    while (t >= TILES - r) { t -= TILES - r; r++; }   // upper-tri decode
    ib = r; jb = r + t;
    if (bid < TRI) { Af = xf; Bf = xf; nA = nx; nB = nx; }
    else           { Af = yf; Bf = yf; nA = ny; nB = ny; }
    isdiag = (ib == jb);
    w = isdiag ? 1.0f : 2.0f;
  } else {
    int t = bid - 2 * TRI;
    ib = t >> 6; jb = t & 63;
    Af = xf; Bf = yf; nA = nx; nB = ny;
    w = -2.0f;
  }

  int tid = threadIdx.x;
  int lane = tid & 63, wv = tid >> 6;
  int wm = wv >> 1, wn = wv & 1;          // 2x2 waves; per-wave 64x64 out
  int r16 = lane & 15, g4 = lane >> 4;

  const unsigned short* Afrag = Af + (size_t)(ib * 8) * 4096;
  const unsigned short* Bfrag = Bf + (size_t)(jb * 8) * 4096;

  // stage one ks-slice: 8 A slots + 8 B slots of 1024 B; 4 slots per wave.
  // LDS dest is wave-uniform base + lane*16 (global_load_lds requirement).
  #define STAGE(ks, buf)                                                        \
    {                                                                           \
      _Pragma("unroll")                                                         \
      for (int i = 0; i < 4; i++) {                                             \
        int s = wv * 4 + i;                                                     \
        const unsigned short* g = (s < 8)                                       \
            ? (Afrag + (size_t)s * 4096 + (ks) * 512 + lane * 8)                \
            : (Bfrag + (size_t)(s - 8) * 4096 + (ks) * 512 + lane * 8);         \
        unsigned short* l = (s < 8) ? &As[buf][s * 512] : &Bs[buf][(s - 8) * 512]; \
        __builtin_amdgcn_global_load_lds(                                       \
            (const __attribute__((address_space(1))) void*)g,                   \
            (__attribute__((address_space(3))) void*)l, 16, 0, 0);              \
      }                                                                         \
    }

  f32x4 acc[4][4];
  #pragma unroll
  for (int m = 0; m < 4; m++)
    #pragma unroll
    for (int n = 0; n < 4; n++) acc[m][n] = (f32x4){0.f, 0.f, 0.f, 0.f};

  STAGE(0, 0);
  __syncthreads();

  #pragma unroll
  for (int ks = 0; ks < 8; ks++) {
    int cur = ks & 1;
    if (ks < 7) STAGE(ks + 1, cur ^ 1);
    bf16x8 a[4], b[4];
    #pragma unroll
    for (int m = 0; m < 4; m++)
      a[m] = *(const bf16x8*)&As[cur][(wm * 4 + m) * 512 + lane * 8];
    #pragma unroll
    for (int n = 0; n < 4; n++)
      b[n] = *(const bf16x8*)&Bs[cur][(wn * 4 + n) * 512 + lane * 8];
    #pragma unroll
    for (int m = 0; m < 4; m++)
      #pragma unroll
      for (int n = 0; n < 4; n++)
        acc[m][n] = __builtin_amdgcn_mfma_f32_16x16x32_bf16(a[m], b[n], acc[m][n], 0, 0, 0);
    __syncthreads();   // drains staging; cross-block overlap hides the stall
  }

  // epilogue: d = n_i + n_j - 2*dot; C/D: col=lane&15, row=(lane>>4)*4+reg
  const float* nArow = nA + ib * 128;
  const float* nBrow = nB + jb * 128;
  float nb4[4];
  #pragma unroll
  for (int n = 0; n < 4; n++) nb4[n] = nBrow[wn * 64 + n * 16 + r16];

  float lsum = 0.f;
  #pragma unroll
  for (int m = 0; m < 4; m++) {
    float na4[4];
    #pragma unroll
    for (int r = 0; r < 4; r++) na4[r] = nArow[wm * 64 + m * 16 + g4 * 4 + r];
    float dv[4][4];
    float dmin = 3.0e38f;
    #pragma unroll
    for (int n = 0; n < 4; n++) {
      #pragma unroll
      for (int r = 0; r < 4; r++) {
        float dd = fmaf(-2.f, acc[m][n][r], na4[r] + nb4[n]);
        dd = fmaxf(dd, 1e-30f);
        int rl = wm * 64 + m * 16 + g4 * 4 + r;
        int cl = wn * 64 + n * 16 + r16;
        if (isdiag && rl == cl) dd = 1e30f;   // diag via diag_kernel; exp->0
        dv[n][r] = dd;
        dmin = fminf(dmin, dd);
      }
    }
    if (__all(dmin > 110.f)) {
      // exp(-g*d) == 0.0f exactly for g>=1 when d>110 (also 0 in reference)
      #pragma unroll
      for (int n = 0; n < 4; n++)
        #pragma unroll
        for (int r = 0; r < 4; r++) {
          float dd = dv[n][r];
          lsum += __expf(dd * -0.001f);
          lsum += __expf(dd * -0.01f);
          lsum += __expf(dd * -0.1f);
        }
    } else {
      #pragma unroll
      for (int n = 0; n < 4; n++)
        #pragma unroll
        for (int r = 0; r < 4; r++) {
          float dd = dv[n][r];
          lsum += __expf(dd * -0.001f);
          lsum += __expf(dd * -0.01f);
          lsum += __expf(dd * -0.1f);
          lsum += __expf(dd * -1.0f);
          lsum += __expf(dd * -10.0f);
          lsum += __expf(dd * -100.0f);
          lsum += __expf(dd * -1000.0f);
        }
    }
  }

  double v = (double)lsum * (double)w;
  v += __shfl_xor(v, 32);
  v += __shfl_xor(v, 16);
  v += __shfl_xor(v, 8);
  v += __shfl_xor(v, 4);
  v += __shfl_xor(v, 2);
  v += __shfl_xor(v, 1);
  if (lane == 0) red[wv] = v;
  __syncthreads();
  if (tid == 0) {
    double s = red[0] + red[1] + red[2] + red[3];
    atomicAdd(acc_out, s);
  }
  #undef STAGE
}

// Fallback (round-2 kernel, no frag arrays) if ws is too small.
__global__ __launch_bounds__(256) void mmd_fallback_kernel(const float* __restrict__ X,
                                                           const float* __restrict__ Y,
                                                           const float* __restrict__ nx,
                                                           const float* __restrict__ ny,
                                                           double* __restrict__ acc_out) {
  __shared__ unsigned short As[128 * 64];
  __shared__ unsigned short Bs[128 * 64];
  __shared__ double red[256];
  int bid = blockIdx.x;
  const float *A, *B, *nA, *nB;
  float w;
  int ib, jb;
  bool isdiag = false;
  if (bid < 2 * TRI) {
    int t = (bid < TRI) ? bid : bid - TRI;
    int r = 0;
    while (t >= TILES - r) { t -= TILES - r; r++; }
    ib = r; jb = r + t;
    if (bid < TRI) { A = X; B = X; nA = nx; nB = nx; }
    else           { A = Y; B = Y; nA = ny; nB = ny; }
    isdiag = (ib == jb);
    w = isdiag ? 1.0f : 2.0f;
  } else {
    int t = bid - 2 * TRI;
    ib = t >> 6; jb = t & 63;
    A = X; B = Y; nA = nx; nB = ny;
    w = -2.0f;
  }
  int tid = threadIdx.x;
  int lane = tid & 63;
  int wv = tid >> 6, wm = wv >> 1, wn = wv & 1;
  int r16 = lane & 15, g4 = lane >> 4;
  const float* Ab = A + (size_t)ib * 128 * D;
  const float* Bb = B + (size_t)jb * 128 * D;
  f32x4 acc[4][4];
  #pragma unroll
  for (int m = 0; m < 4; m++)
    #pragma unroll
    for (int n = 0; n < 4; n++) acc[m][n] = (f32x4){0.f, 0.f, 0.f, 0.f};
  #pragma unroll 1
  for (int kc = 0; kc < 4; kc++) {
    int k0f = (kc & 1) * 64;
    bool ishi = (kc < 2);
    __syncthreads();
    #pragma unroll
    for (int s = 0; s < 4; s++) {
      int slot = tid + s * 256;
      int row = slot >> 3;
      int k2 = (slot & 7) * 8;
      const float* pa = Ab + row * D + k0f + k2;
      const float* pb = Bb + row * D + k0f + k2;
      float4 a0 = *(const float4*)pa;
      float4 a1 = *(const float4*)(pa + 4);
      float4 b0 = *(const float4*)pb;
      float4 b1 = *(const float4*)(pb + 4);
      float av[8] = {a0.x, a0.y, a0.z, a0.w, a1.x, a1.y, a1.z, a1.w};
      float bv[8] = {b0.x, b0.y, b0.z, b0.w, b1.x, b1.y, b1.z, b1.w};
      u16x8 ua, ub;
      #pragma unroll
      for (int j = 0; j < 8; j++) {
        unsigned short ha = f2bf(av[j]);
        unsigned short hb = f2bf(bv[j]);
        if (ishi) { ua[j] = (short)ha; ub[j] = (short)hb; }
        else {
          ua[j] = f2bf(av[j] - bf2f(ha));
          ub[j] = f2bf(bv[j] - bf2f(hb));
        }
      }
      int boff = row * 128 + ((k2 * 2) ^ ((row & 7) << 4));
      *(u16x8*)((char*)As + boff) = ua;
      *(u16x8*)((char*)Bs + boff) = ub;
    }
    __syncthreads();
    #pragma unroll
    for (int ks = 0; ks < 2; ks++) {
      bf16x8 af[4], bfr[4];
      int kb = ks * 64 + g4 * 16;
      #pragma unroll
      for (int m = 0; m < 4; m++) {
        int row = wm * 64 + m * 16 + r16;
        af[m] = *(const bf16x8*)((const char*)As + row * 128 + (kb ^ ((row & 7) << 4)));
      }
      #pragma unroll
      for (int n = 0; n < 4; n++) {
        int row = wn * 64 + n * 16 + r16;
        bfr[n] = *(const bf16x8*)((const char*)Bs + row * 128 + (kb ^ ((row & 7) << 4)));
      }
      #pragma unroll
      for (int m = 0; m < 4; m++)
        #pragma unroll
        for (int n = 0; n < 4; n++)
          acc[m][n] = __builtin_amdgcn_mfma_f32_16x16x32_bf16(af[m], bfr[n], acc[m][n], 0, 0, 0);
    }
  }
  const float* nArow = nA + ib * 128;
  const float* nBrow = nB + jb * 128;
  float nb4[4];
  #pragma unroll
  for (int n = 0; n < 4; n++) nb4[n] = nBrow[wn * 64 + n * 16 + r16];
  float lsum = 0.f;
  #pragma unroll
  for (int m = 0; m < 4; m++) {
    float na4[4];
    #pragma unroll
    for (int r = 0; r < 4; r++) na4[r] = nArow[wm * 64 + m * 16 + g4 * 4 + r];
    float dv[4][4];
    float dmin = 3.0e38f;
    #pragma unroll
    for (int n = 0; n < 4; n++) {
      #pragma unroll
      for (int r = 0; r < 4; r++) {
        float dd = fmaf(-2.f, acc[m][n][r], na4[r] + nb4[n]);
        dd = fmaxf(dd, 1e-30f);
        int rl = wm * 64 + m * 16 + g4 * 4 + r;
        int cl = wn * 64 + n * 16 + r16;
        if (isdiag && rl == cl) dd = 1e30f;
        dv[n][r] = dd;
        dmin = fminf(dmin, dd);
      }
    }
    if (__all(dmin > 110.f)) {
      #pragma unroll
      for (int n = 0; n < 4; n++)
        #pragma unroll
        for (int r = 0; r < 4; r++) {
          float dd = dv[n][r];
          lsum += __expf(dd * -0.001f);
          lsum += __expf(dd * -0.01f);
          lsum += __expf(dd * -0.1f);
        }
    } else {
      #pragma unroll
      for (int n = 0; n < 4; n++)
        #pragma unroll
        for (int r = 0; r < 4; r++) {
          float dd = dv[n][r];
          lsum += __expf(dd * -0.001f);
          lsum += __expf(dd * -0.01f);
          lsum += __expf(dd * -0.1f);
          lsum += __expf(dd * -1.0f);
          lsum += __expf(dd * -10.0f);
          lsum += __expf(dd * -100.0f);
          lsum += __expf(dd * -1000.0f);
        }
    }
  }
  red[tid] = (double)lsum * (double)w;
  __syncthreads();
  #pragma unroll
  for (int s = 128; s > 0; s >>= 1) {
    if (tid < s) red[tid] += red[tid + s];
    __syncthreads();
  }
  if (tid == 0) atomicAdd(acc_out, red[0]);
}

__global__ __launch_bounds__(256) void diag_kernel(const float* __restrict__ x,
                                                   const float* __restrict__ y,
                                                   const float* __restrict__ nx,
                                                   const float* __restrict__ ny,
                                                   double* __restrict__ acc_out) {
  __shared__ double red[256];
  int tid = threadIdx.x;
  int idx = (int)blockIdx.x * 256 + tid;
  int arr = idx >> 13;
  int row = idx & 8191;
  const float* src = (arr ? y : x) + (size_t)row * D;
  float n = (arr ? ny : nx)[row];
  float acc = 0.f;
  #pragma unroll 4
  for (int k4 = 0; k4 < 32; k4++) {
    float4 v = *(const float4*)(src + k4 * 4);
    acc = fmaf(v.x, v.x, acc);
    acc = fmaf(v.y, v.y, acc);
    acc = fmaf(v.z, v.z, acc);
    acc = fmaf(v.w, v.w, acc);
  }
  float d = fmaf(-2.f, acc, n + n);
  d = fmaxf(d, 1e-30f);
  float s = 0.f;
  s += __expf(d * -0.001f);
  s += __expf(d * -0.01f);
  s += __expf(d * -0.1f);
  s += __expf(d * -1.0f);
  s += __expf(d * -10.0f);
  s += __expf(d * -100.0f);
  s += __expf(d * -1000.0f);
  red[tid] = (double)s;
  __syncthreads();
  #pragma unroll
  for (int st = 128; st > 0; st >>= 1) {
    if (tid < st) red[tid] += red[tid + st];
    __syncthreads();
  }
  if (tid == 0) atomicAdd(acc_out, red[0]);
}

__global__ void finalize_kernel(const double* __restrict__ acc,
                                float* __restrict__ out) {
  out[0] = (float)(acc[0] * (1.0 / ((double)N_PTS * (double)N_PTS)));
}

extern "C" void kernel_launch(void* const* d_in, const int* in_sizes, int n_in,
                              void* d_out, int out_size, void* d_ws, size_t ws_size,
                              hipStream_t stream) {
  const float* x = (const float*)d_in[0];
  const float* y = (const float*)d_in[1];
  float* out = (float*)d_out;

  char* ws = (char*)d_ws;
  double* acc = (double*)ws;                       // 8 B
  float* nx = (float*)(ws + 4096);                 // 8192 f
  float* ny = (float*)(ws + 36864);                // 8192 f
  const size_t FRAG_OFF = 69632;
  const size_t FRAG_SZ = 4194304;                  // 4 MB each
  const size_t NEED = FRAG_OFF + 2 * FRAG_SZ;      // proven fit (rounds 5/6)

  hipMemsetAsync(acc, 0, sizeof(double), stream);
  hipLaunchKernelGGL(norms_kernel, dim3(256), dim3(256), 0, stream, x, y, nx, ny);
  if (ws_size >= NEED) {
    unsigned short* xf = (unsigned short*)(ws + FRAG_OFF);
    unsigned short* yf = (unsigned short*)(ws + FRAG_OFF + FRAG_SZ);
    hipLaunchKernelGGL(convert_kernel, dim3(256), dim3(256), 0, stream, x, y, xf, yf);
    hipLaunchKernelGGL(mmd_tile128_kernel, dim3(NBLK), dim3(256), 0, stream,
                       xf, yf, nx, ny, acc);
  } else {
    hipLaunchKernelGGL(mmd_fallback_kernel, dim3(NBLK), dim3(256), 0, stream, x, y, nx, ny, acc);
  }
  hipLaunchKernelGGL(diag_kernel, dim3(64), dim3(256), 0, stream, x, y, nx, ny, acc);
  hipLaunchKernelGGL(finalize_kernel, dim3(1), dim3(1), 0, stream, acc, out);
}

// Round 10
// 210.161 us; speedup vs baseline: 2.5619x; 1.0318x over previous
//
#include <hip/hip_runtime.h>

// MMD, 7-gamma Gaussian kernel, x,y: [8192,128] fp32.
// Round 10: round-7 structure with ONE change: __launch_bounds__(256,4) ->
// __launch_bounds__(256). Round-9 counters showed the (256,4) clamp capped
// arch VGPRs at 64 (unified file: acc[4][4] f32x4 = 64 AGPRs ate the rest),
// spilling operands to scratch: WRITE_SIZE 129 MB + FETCH +61 MB of pure
// spill traffic (19% HBM). Freeing the allocator removes the spill.
// Structure: 128x128 tiles, 4 waves, K'=32 chunks staged via global_load_lds,
// double-buffered, 32 KB LDS/block -> ~3-4 blocks/CU (cross-block overlap).
// Fragment array layout (verified rounds 2/5/6/9): [rowgrp][ks][lane][8] bf16,
// rowgrp stride 4096 ushorts, ks stride 512; serves both A and B operands.
// Numerics bit-identical to rounds 5/6/9 (ks 0..7 in-order accumulation).
// Diagonal patched by exact-fp32 diag_kernel (bit-exact vs round-1 baseline).

#define N_PTS 8192
#define D 128
#define TILES 64
#define TRI 2080
#define NBLK (2 * TRI + TILES * TILES)

typedef __attribute__((ext_vector_type(8))) short bf16x8;
typedef __attribute__((ext_vector_type(8))) unsigned short u16x8;
typedef __attribute__((ext_vector_type(4))) float f32x4;

__device__ __forceinline__ unsigned short f2bf(float a) {  // RNE
  unsigned u = __float_as_uint(a);
  return (unsigned short)((u + 0x7FFFu + ((u >> 16) & 1u)) >> 16);
}
__device__ __forceinline__ float bf2f(unsigned short b) {
  return __uint_as_float(((unsigned)b) << 16);
}

__global__ __launch_bounds__(256) void norms_kernel(const float* __restrict__ x,
                                                    const float* __restrict__ y,
                                                    float* __restrict__ nx,
                                                    float* __restrict__ ny) {
  int tid = threadIdx.x;
  int g = tid & 3;
  int row = ((int)blockIdx.x & 127) * 64 + (tid >> 2);
  int arr = (int)blockIdx.x >> 7;
  const float* src = arr ? y : x;
  const float4* p = (const float4*)(src + (size_t)row * D) + g;
  float s = 0.f;
  #pragma unroll
  for (int i = 0; i < 8; i++) {
    float4 v = p[i * 4];
    s += v.x * v.x + v.y * v.y + v.z * v.z + v.w * v.w;
  }
  s += __shfl_xor(s, 1);
  s += __shfl_xor(s, 2);
  if (g == 0) (arr ? ny : nx)[row] = s;
}

// x,y -> fragment-ordered bf16 hi|lo arrays. 1 wave per 16-row group.
__global__ __launch_bounds__(256) void convert_kernel(const float* __restrict__ x,
                                                      const float* __restrict__ y,
                                                      unsigned short* __restrict__ xf,
                                                      unsigned short* __restrict__ yf) {
  __shared__ float lds[4][16][132];
  int tid = threadIdx.x;
  int lane = tid & 63, wv = tid >> 6;
  int grp = (int)blockIdx.x * 4 + wv;
  int arr = grp >> 9;
  int rowgrp = grp & 511;
  const float* src = (arr ? y : x) + (size_t)rowgrp * 16 * D;
  unsigned short* dst = (arr ? yf : xf) + (size_t)rowgrp * 4096;

  #pragma unroll
  for (int it = 0; it < 8; it++) {
    int slot = it * 64 + lane;
    int row = slot >> 5, f4 = slot & 31;
    float4 v = *(const float4*)(src + row * D + f4 * 4);
    *(float4*)&lds[wv][row][f4 * 4] = v;
  }
  __syncthreads();

  int row = lane & 15, koct = lane >> 4;
  #pragma unroll
  for (int ks = 0; ks < 8; ks++) {
    int kp = ks * 32 + koct * 8;
    int kf = kp & 127;
    bool ishi = kp < 128;
    float v[8];
    *(float4*)&v[0] = *(const float4*)&lds[wv][row][kf];
    *(float4*)&v[4] = *(const float4*)&lds[wv][row][kf + 4];
    u16x8 o;
    #pragma unroll
    for (int j = 0; j < 8; j++) {
      unsigned short h = f2bf(v[j]);
      o[j] = ishi ? h : f2bf(v[j] - bf2f(h));
    }
    *(u16x8*)(dst + ks * 512 + lane * 8) = o;
  }
}

__global__ __launch_bounds__(256) void mmd_tile128_kernel(
    const unsigned short* __restrict__ xf, const unsigned short* __restrict__ yf,
    const float* __restrict__ nx, const float* __restrict__ ny,
    double* __restrict__ acc_out) {
  __shared__ unsigned short As[2][4096];   // [buf][rg(8)*512], 8 KB each
  __shared__ unsigned short Bs[2][4096];
  __shared__ double red[4];

  int bid = blockIdx.x;
  const unsigned short *Af, *Bf;
  const float *nA, *nB;
  float w;
  int ib, jb;
  bool isdiag = false;
  if (bid < 2 * TRI) {
    int t = (bid < TRI) ? bid : bid - TRI;
    int r = 0;
    while (t >= TILES - r) { t -= TILES - r; r++; }   // upper-tri decode
    ib = r; jb = r + t;
    if (bid < TRI) { Af = xf; Bf = xf; nA = nx; nB = nx; }
    else           { Af = yf; Bf = yf; nA = ny; nB = ny; }
    isdiag = (ib == jb);
    w = isdiag ? 1.0f : 2.0f;
  } else {
    int t = bid - 2 * TRI;
    ib = t >> 6; jb = t & 63;
    Af = xf; Bf = yf; nA = nx; nB = ny;
    w = -2.0f;
  }

  int tid = threadIdx.x;
  int lane = tid & 63, wv = tid >> 6;
  int wm = wv >> 1, wn = wv & 1;          // 2x2 waves; per-wave 64x64 out
  int r16 = lane & 15, g4 = lane >> 4;

  const unsigned short* Afrag = Af + (size_t)(ib * 8) * 4096;
  const unsigned short* Bfrag = Bf + (size_t)(jb * 8) * 4096;

  // stage one ks-slice: 8 A slots + 8 B slots of 1024 B; 4 slots per wave.
  // LDS dest is wave-uniform base + lane*16 (global_load_lds requirement).
  #define STAGE(ks, buf)                                                        \
    {                                                                           \
      _Pragma("unroll")                                                         \
      for (int i = 0; i < 4; i++) {                                             \
        int s = wv * 4 + i;                                                     \
        const unsigned short* g = (s < 8)                                       \
            ? (Afrag + (size_t)s * 4096 + (ks) * 512 + lane * 8)                \
            : (Bfrag + (size_t)(s - 8) * 4096 + (ks) * 512 + lane * 8);         \
        unsigned short* l = (s < 8) ? &As[buf][s * 512] : &Bs[buf][(s - 8) * 512]; \
        __builtin_amdgcn_global_load_lds(                                       \
            (const __attribute__((address_space(1))) void*)g,                   \
            (__attribute__((address_space(3))) void*)l, 16, 0, 0);              \
      }                                                                         \
    }

  f32x4 acc[4][4];
  #pragma unroll
  for (int m = 0; m < 4; m++)
    #pragma unroll
    for (int n = 0; n < 4; n++) acc[m][n] = (f32x4){0.f, 0.f, 0.f, 0.f};

  STAGE(0, 0);
  __syncthreads();

  #pragma unroll
  for (int ks = 0; ks < 8; ks++) {
    int cur = ks & 1;
    if (ks < 7) STAGE(ks + 1, cur ^ 1);
    bf16x8 a[4], b[4];
    #pragma unroll
    for (int m = 0; m < 4; m++)
      a[m] = *(const bf16x8*)&As[cur][(wm * 4 + m) * 512 + lane * 8];
    #pragma unroll
    for (int n = 0; n < 4; n++)
      b[n] = *(const bf16x8*)&Bs[cur][(wn * 4 + n) * 512 + lane * 8];
    #pragma unroll
    for (int m = 0; m < 4; m++)
      #pragma unroll
      for (int n = 0; n < 4; n++)
        acc[m][n] = __builtin_amdgcn_mfma_f32_16x16x32_bf16(a[m], b[n], acc[m][n], 0, 0, 0);
    __syncthreads();   // drains staging; cross-block overlap hides the stall
  }

  // epilogue: d = n_i + n_j - 2*dot; C/D: col=lane&15, row=(lane>>4)*4+reg
  const float* nArow = nA + ib * 128;
  const float* nBrow = nB + jb * 128;
  float nb4[4];
  #pragma unroll
  for (int n = 0; n < 4; n++) nb4[n] = nBrow[wn * 64 + n * 16 + r16];

  float lsum = 0.f;
  #pragma unroll
  for (int m = 0; m < 4; m++) {
    float na4[4];
    #pragma unroll
    for (int r = 0; r < 4; r++) na4[r] = nArow[wm * 64 + m * 16 + g4 * 4 + r];
    float dv[4][4];
    float dmin = 3.0e38f;
    #pragma unroll
    for (int n = 0; n < 4; n++) {
      #pragma unroll
      for (int r = 0; r < 4; r++) {
        float dd = fmaf(-2.f, acc[m][n][r], na4[r] + nb4[n]);
        dd = fmaxf(dd, 1e-30f);
        int rl = wm * 64 + m * 16 + g4 * 4 + r;
        int cl = wn * 64 + n * 16 + r16;
        if (isdiag && rl == cl) dd = 1e30f;   // diag via diag_kernel; exp->0
        dv[n][r] = dd;
        dmin = fminf(dmin, dd);
      }
    }
    if (__all(dmin > 110.f)) {
      // exp(-g*d) == 0.0f exactly for g>=1 when d>110 (also 0 in reference)
      #pragma unroll
      for (int n = 0; n < 4; n++)
        #pragma unroll
        for (int r = 0; r < 4; r++) {
          float dd = dv[n][r];
          lsum += __expf(dd * -0.001f);
          lsum += __expf(dd * -0.01f);
          lsum += __expf(dd * -0.1f);
        }
    } else {
      #pragma unroll
      for (int n = 0; n < 4; n++)
        #pragma unroll
        for (int r = 0; r < 4; r++) {
          float dd = dv[n][r];
          lsum += __expf(dd * -0.001f);
          lsum += __expf(dd * -0.01f);
          lsum += __expf(dd * -0.1f);
          lsum += __expf(dd * -1.0f);
          lsum += __expf(dd * -10.0f);
          lsum += __expf(dd * -100.0f);
          lsum += __expf(dd * -1000.0f);
        }
    }
  }

  double v = (double)lsum * (double)w;
  v += __shfl_xor(v, 32);
  v += __shfl_xor(v, 16);
  v += __shfl_xor(v, 8);
  v += __shfl_xor(v, 4);
  v += __shfl_xor(v, 2);
  v += __shfl_xor(v, 1);
  if (lane == 0) red[wv] = v;
  __syncthreads();
  if (tid == 0) {
    double s = red[0] + red[1] + red[2] + red[3];
    atomicAdd(acc_out, s);
  }
  #undef STAGE
}

// Fallback (round-2 kernel, no frag arrays) if ws is too small.
__global__ __launch_bounds__(256) void mmd_fallback_kernel(const float* __restrict__ X,
                                                           const float* __restrict__ Y,
                                                           const float* __restrict__ nx,
                                                           const float* __restrict__ ny,
                                                           double* __restrict__ acc_out) {
  __shared__ unsigned short As[128 * 64];
  __shared__ unsigned short Bs[128 * 64];
  __shared__ double red[256];
  int bid = blockIdx.x;
  const float *A, *B, *nA, *nB;
  float w;
  int ib, jb;
  bool isdiag = false;
  if (bid < 2 * TRI) {
    int t = (bid < TRI) ? bid : bid - TRI;
    int r = 0;
    while (t >= TILES - r) { t -= TILES - r; r++; }
    ib = r; jb = r + t;
    if (bid < TRI) { A = X; B = X; nA = nx; nB = nx; }
    else           { A = Y; B = Y; nA = ny; nB = ny; }
    isdiag = (ib == jb);
    w = isdiag ? 1.0f : 2.0f;
  } else {
    int t = bid - 2 * TRI;
    ib = t >> 6; jb = t & 63;
    A = X; B = Y; nA = nx; nB = ny;
    w = -2.0f;
  }
  int tid = threadIdx.x;
  int lane = tid & 63;
  int wv = tid >> 6, wm = wv >> 1, wn = wv & 1;
  int r16 = lane & 15, g4 = lane >> 4;
  const float* Ab = A + (size_t)ib * 128 * D;
  const float* Bb = B + (size_t)jb * 128 * D;
  f32x4 acc[4][4];
  #pragma unroll
  for (int m = 0; m < 4; m++)
    #pragma unroll
    for (int n = 0; n < 4; n++) acc[m][n] = (f32x4){0.f, 0.f, 0.f, 0.f};
  #pragma unroll 1
  for (int kc = 0; kc < 4; kc++) {
    int k0f = (kc & 1) * 64;
    bool ishi = (kc < 2);
    __syncthreads();
    #pragma unroll
    for (int s = 0; s < 4; s++) {
      int slot = tid + s * 256;
      int row = slot >> 3;
      int k2 = (slot & 7) * 8;
      const float* pa = Ab + row * D + k0f + k2;
      const float* pb = Bb + row * D + k0f + k2;
      float4 a0 = *(const float4*)pa;
      float4 a1 = *(const float4*)(pa + 4);
      float4 b0 = *(const float4*)pb;
      float4 b1 = *(const float4*)(pb + 4);
      float av[8] = {a0.x, a0.y, a0.z, a0.w, a1.x, a1.y, a1.z, a1.w};
      float bv[8] = {b0.x, b0.y, b0.z, b0.w, b1.x, b1.y, b1.z, b1.w};
      u16x8 ua, ub;
      #pragma unroll
      for (int j = 0; j < 8; j++) {
        unsigned short ha = f2bf(av[j]);
        unsigned short hb = f2bf(bv[j]);
        if (ishi) { ua[j] = (short)ha; ub[j] = (short)hb; }
        else {
          ua[j] = f2bf(av[j] - bf2f(ha));
          ub[j] = f2bf(bv[j] - bf2f(hb));
        }
      }
      int boff = row * 128 + ((k2 * 2) ^ ((row & 7) << 4));
      *(u16x8*)((char*)As + boff) = ua;
      *(u16x8*)((char*)Bs + boff) = ub;
    }
    __syncthreads();
    #pragma unroll
    for (int ks = 0; ks < 2; ks++) {
      bf16x8 af[4], bfr[4];
      int kb = ks * 64 + g4 * 16;
      #pragma unroll
      for (int m = 0; m < 4; m++) {
        int row = wm * 64 + m * 16 + r16;
        af[m] = *(const bf16x8*)((const char*)As + row * 128 + (kb ^ ((row & 7) << 4)));
      }
      #pragma unroll
      for (int n = 0; n < 4; n++) {
        int row = wn * 64 + n * 16 + r16;
        bfr[n] = *(const bf16x8*)((const char*)Bs + row * 128 + (kb ^ ((row & 7) << 4)));
      }
      #pragma unroll
      for (int m = 0; m < 4; m++)
        #pragma unroll
        for (int n = 0; n < 4; n++)
          acc[m][n] = __builtin_amdgcn_mfma_f32_16x16x32_bf16(af[m], bfr[n], acc[m][n], 0, 0, 0);
    }
  }
  const float* nArow = nA + ib * 128;
  const float* nBrow = nB + jb * 128;
  float nb4[4];
  #pragma unroll
  for (int n = 0; n < 4; n++) nb4[n] = nBrow[wn * 64 + n * 16 + r16];
  float lsum = 0.f;
  #pragma unroll
  for (int m = 0; m < 4; m++) {
    float na4[4];
    #pragma unroll
    for (int r = 0; r < 4; r++) na4[r] = nArow[wm * 64 + m * 16 + g4 * 4 + r];
    float dv[4][4];
    float dmin = 3.0e38f;
    #pragma unroll
    for (int n = 0; n < 4; n++) {
      #pragma unroll
      for (int r = 0; r < 4; r++) {
        float dd = fmaf(-2.f, acc[m][n][r], na4[r] + nb4[n]);
        dd = fmaxf(dd, 1e-30f);
        int rl = wm * 64 + m * 16 + g4 * 4 + r;
        int cl = wn * 64 + n * 16 + r16;
        if (isdiag && rl == cl) dd = 1e30f;
        dv[n][r] = dd;
        dmin = fminf(dmin, dd);
      }
    }
    if (__all(dmin > 110.f)) {
      #pragma unroll
      for (int n = 0; n < 4; n++)
        #pragma unroll
        for (int r = 0; r < 4; r++) {
          float dd = dv[n][r];
          lsum += __expf(dd * -0.001f);
          lsum += __expf(dd * -0.01f);
          lsum += __expf(dd * -0.1f);
        }
    } else {
      #pragma unroll
      for (int n = 0; n < 4; n++)
        #pragma unroll
        for (int r = 0; r < 4; r++) {
          float dd = dv[n][r];
          lsum += __expf(dd * -0.001f);
          lsum += __expf(dd * -0.01f);
          lsum += __expf(dd * -0.1f);
          lsum += __expf(dd * -1.0f);
          lsum += __expf(dd * -10.0f);
          lsum += __expf(dd * -100.0f);
          lsum += __expf(dd * -1000.0f);
        }
    }
  }
  red[tid] = (double)lsum * (double)w;
  __syncthreads();
  #pragma unroll
  for (int s = 128; s > 0; s >>= 1) {
    if (tid < s) red[tid] += red[tid + s];
    __syncthreads();
  }
  if (tid == 0) atomicAdd(acc_out, red[0]);
}

__global__ __launch_bounds__(256) void diag_kernel(const float* __restrict__ x,
                                                   const float* __restrict__ y,
                                                   const float* __restrict__ nx,
                                                   const float* __restrict__ ny,
                                                   double* __restrict__ acc_out) {
  __shared__ double red[256];
  int tid = threadIdx.x;
  int idx = (int)blockIdx.x * 256 + tid;
  int arr = idx >> 13;
  int row = idx & 8191;
  const float* src = (arr ? y : x) + (size_t)row * D;
  float n = (arr ? ny : nx)[row];
  float acc = 0.f;
  #pragma unroll 4
  for (int k4 = 0; k4 < 32; k4++) {
    float4 v = *(const float4*)(src + k4 * 4);
    acc = fmaf(v.x, v.x, acc);
    acc = fmaf(v.y, v.y, acc);
    acc = fmaf(v.z, v.z, acc);
    acc = fmaf(v.w, v.w, acc);
  }
  float d = fmaf(-2.f, acc, n + n);
  d = fmaxf(d, 1e-30f);
  float s = 0.f;
  s += __expf(d * -0.001f);
  s += __expf(d * -0.01f);
  s += __expf(d * -0.1f);
  s += __expf(d * -1.0f);
  s += __expf(d * -10.0f);
  s += __expf(d * -100.0f);
  s += __expf(d * -1000.0f);
  red[tid] = (double)s;
  __syncthreads();
  #pragma unroll
  for (int st = 128; st > 0; st >>= 1) {
    if (tid < st) red[tid] += red[tid + st];
    __syncthreads();
  }
  if (tid == 0) atomicAdd(acc_out, red[0]);
}

__global__ void finalize_kernel(const double* __restrict__ acc,
                                float* __restrict__ out) {
  out[0] = (float)(acc[0] * (1.0 / ((double)N_PTS * (double)N_PTS)));
}

extern "C" void kernel_launch(void* const* d_in, const int* in_sizes, int n_in,
                              void* d_out, int out_size, void* d_ws, size_t ws_size,
                              hipStream_t stream) {
  const float* x = (const float*)d_in[0];
  const float* y = (const float*)d_in[1];
  float* out = (float*)d_out;

  char* ws = (char*)d_ws;
  double* acc = (double*)ws;                       // 8 B
  float* nx = (float*)(ws + 4096);                 // 8192 f
  float* ny = (float*)(ws + 36864);                // 8192 f
  const size_t FRAG_OFF = 69632;
  const size_t FRAG_SZ = 4194304;                  // 4 MB each
  const size_t NEED = FRAG_OFF + 2 * FRAG_SZ;      // proven fit (rounds 5/6/9)

  hipMemsetAsync(acc, 0, sizeof(double), stream);
  hipLaunchKernelGGL(norms_kernel, dim3(256), dim3(256), 0, stream, x, y, nx, ny);
  if (ws_size >= NEED) {
    unsigned short* xf = (unsigned short*)(ws + FRAG_OFF);
    unsigned short* yf = (unsigned short*)(ws + FRAG_OFF + FRAG_SZ);
    hipLaunchKernelGGL(convert_kernel, dim3(256), dim3(256), 0, stream, x, y, xf, yf);
    hipLaunchKernelGGL(mmd_tile128_kernel, dim3(NBLK), dim3(256), 0, stream,
                       xf, yf, nx, ny, acc);
  } else {
    hipLaunchKernelGGL(mmd_fallback_kernel, dim3(NBLK), dim3(256), 0, stream, x, y, nx, ny, acc);
  }
  hipLaunchKernelGGL(diag_kernel, dim3(64), dim3(256), 0, stream, x, y, nx, ny, acc);
  hipLaunchKernelGGL(finalize_kernel, dim3(1), dim3(1), 0, stream, acc, out);
}